// Round 2
// baseline (976.681 us; speedup 1.0000x reference)
//
#include <hip/hip_runtime.h>

typedef _Float16 half_t;
typedef _Float16 half8 __attribute__((ext_vector_type(8)));
typedef _Float16 half4v __attribute__((ext_vector_type(4)));
typedef _Float16 half2v __attribute__((ext_vector_type(2)));
typedef float floatx4 __attribute__((ext_vector_type(4)));

#define TOK 4096
#define DIM 4096
#define S_LEN 1024
#define B_SZ 4
#define HQ_N 32
#define HKV_N 8
#define HD_N 128
#define L_KV 2048
#define NKV 1024
#define QK_SCALE 0.08838834764831845f

__device__ __forceinline__ void gload_lds16(const void* g, void* l) {
  __builtin_amdgcn_global_load_lds(
      (const __attribute__((address_space(1))) unsigned int*)g,
      (__attribute__((address_space(3))) unsigned int*)l, 16, 0, 0);
}

// ---------------- elementwise f32 -> f16 ----------------
__global__ __launch_bounds__(256) void conv_x_kernel(const float* __restrict__ x,
                                                     half_t* __restrict__ xh) {
  int t = blockIdx.x * 256 + threadIdx.x;           // one float4 per thread
  floatx4 v = *((const floatx4*)x + t);
  half4v o;
  o[0] = (half_t)v[0]; o[1] = (half_t)v[1]; o[2] = (half_t)v[2]; o[3] = (half_t)v[3];
  *((half4v*)xh + t) = o;
}

// ---------------- transpose + convert: out[n][k] = f16(in[k][n]) ----------------
__global__ __launch_bounds__(256) void conv_transpose(const float* __restrict__ in,
                                                      half_t* __restrict__ out,
                                                      int K, int N) {
  __shared__ half_t T[64 * 65];
  const int tid = threadIdx.x;
  const int n0 = blockIdx.x * 64, k0 = blockIdx.y * 64;
  #pragma unroll
  for (int i = 0; i < 16; ++i) {
    int idx = i * 256 + tid;
    int r = idx >> 6, c = idx & 63;                  // r: K-row, c: N-col
    T[c * 65 + r] = (half_t)in[(size_t)(k0 + r) * N + n0 + c];
  }
  __syncthreads();
  #pragma unroll
  for (int i = 0; i < 16; ++i) {
    int idx = i * 256 + tid;
    int rn = idx >> 6, ck = idx & 63;
    out[(size_t)(n0 + rn) * K + k0 + ck] = T[rn * 65 + ck];
  }
}

// ---------------- GEMM: C[M][N] = A[M][K] * BT[N][K]^T, f16 in, OT out ----------------
template <typename OT>
__global__ __launch_bounds__(256) void gemm_f16(const half_t* __restrict__ A,
                                                const half_t* __restrict__ BT,
                                                OT* __restrict__ C,
                                                int M, int N, int K) {
  __shared__ half_t As[128 * 32];
  __shared__ half_t Bs[128 * 32];
  const int tid = threadIdx.x;
  const int lane = tid & 63;
  const int w = tid >> 6;
  const int wr = w >> 1, wc = w & 1;
  const int g = lane >> 4, qr = lane & 15;
  const int m0 = blockIdx.y * 128, n0 = blockIdx.x * 128;
  floatx4 acc[4][4] = {};
  const int chb0 = tid & 192;                        // wave-uniform
  for (int k0 = 0; k0 < K; k0 += 32) {
    #pragma unroll
    for (int i = 0; i < 2; ++i) {
      int chb = chb0 + 256 * i;
      int ch = chb + lane;
      int row = ch >> 2, c8 = ch & 3;
      gload_lds16(A + (size_t)(m0 + row) * K + k0 + c8 * 8, (char*)As + chb * 16);
      gload_lds16(BT + (size_t)(n0 + row) * K + k0 + c8 * 8, (char*)Bs + chb * 16);
    }
    __syncthreads();
    half8 af[4], bf[4];
    const int koff = g * 8;
    #pragma unroll
    for (int m = 0; m < 4; ++m)
      af[m] = *(const half8*)&As[(wr * 64 + m * 16 + qr) * 32 + koff];
    #pragma unroll
    for (int n = 0; n < 4; ++n)
      bf[n] = *(const half8*)&Bs[(wc * 64 + n * 16 + qr) * 32 + koff];
    #pragma unroll
    for (int m = 0; m < 4; ++m)
      #pragma unroll
      for (int n = 0; n < 4; ++n)
        acc[m][n] = __builtin_amdgcn_mfma_f32_16x16x32_f16(af[m], bf[n], acc[m][n], 0, 0, 0);
    __syncthreads();
  }
  #pragma unroll
  for (int m = 0; m < 4; ++m) {
    int rb = m0 + wr * 64 + m * 16 + g * 4;
    #pragma unroll
    for (int n = 0; n < 4; ++n) {
      int col = n0 + wc * 64 + n * 16 + qr;
      #pragma unroll
      for (int r = 0; r < 4; ++r)
        C[(size_t)(rb + r) * N + col] = (OT)acc[m][n][r];
    }
  }
}

// ---------------- pack q: rope + scale, [tok][HQ*HD] f16 -> [B][HQ][S][HD] f16 ----------------
__global__ __launch_bounds__(256) void pack_q_kernel(const half_t* __restrict__ qf,
                                                     const float* __restrict__ cosT,
                                                     const float* __restrict__ sinT,
                                                     half_t* __restrict__ qh) {
  int t = blockIdx.x * 256 + threadIdx.x;            // B*S*HQ*64 = 8388608
  int j = t & 63;
  int hq = (t >> 6) & 31;
  int tok = t >> 11;
  int s = tok & 1023;
  int b = tok >> 10;
  const half_t* src = qf + (size_t)tok * DIM + hq * HD_N + 2 * j;
  float xr = (float)src[0], xi = (float)src[1];
  float c = cosT[s * 64 + j], sn = sinT[s * 64 + j];
  half2v o;
  o[0] = (half_t)((xr * c - xi * sn) * QK_SCALE);
  o[1] = (half_t)((xr * sn + xi * c) * QK_SCALE);
  *(half2v*)(qh + ((size_t)((b * HQ_N + hq) * S_LEN + s)) * HD_N + 2 * j) = o;
}

// ---------------- pack keys: cache (as-is) + rope(new) -> [B][HKV][L][HD] f16 ----------------
__global__ __launch_bounds__(256) void pack_k_kernel(const half_t* __restrict__ kf,
                                                     const float* __restrict__ cache_k,
                                                     const float* __restrict__ cosT,
                                                     const float* __restrict__ sinT,
                                                     half_t* __restrict__ kh) {
  int t = blockIdx.x * 256 + threadIdx.x;            // B*L*HKV*64 = 4194304
  int j = t & 63;
  int h = (t >> 6) & 7;
  int pos = (t >> 9) & 2047;
  int b = t >> 20;
  float xr, xi;
  if (pos < 1024) {
    const float* src = cache_k + ((size_t)(b * L_KV + pos) * HKV_N + h) * HD_N + 2 * j;
    xr = src[0]; xi = src[1];
  } else {
    int s = pos - 1024;
    const half_t* src = kf + (size_t)(b * S_LEN + s) * NKV + h * HD_N + 2 * j;
    float r0 = (float)src[0], i0 = (float)src[1];
    float c = cosT[s * 64 + j], sn = sinT[s * 64 + j];
    xr = r0 * c - i0 * sn;
    xi = r0 * sn + i0 * c;
  }
  half2v o; o[0] = (half_t)xr; o[1] = (half_t)xi;
  *(half2v*)(kh + ((size_t)(b * HKV_N + h) * L_KV + pos) * HD_N + 2 * j) = o;
}

// ---------------- pack values transposed: -> [B][HKV][HD][L] f16 ----------------
__global__ __launch_bounds__(256) void pack_vt_kernel(const half_t* __restrict__ vf,
                                                      const float* __restrict__ cache_v,
                                                      half_t* __restrict__ vt) {
  __shared__ half_t T[128 * 129];
  const int tid = threadIdx.x;
  const int blk = blockIdx.x;                        // B*HKV*16 = 512
  const int pt = blk & 15;
  const int h = (blk >> 4) & 7;
  const int b = blk >> 7;
  const int p0 = pt * 128;
  #pragma unroll
  for (int i = 0; i < 64; ++i) {
    int idx = i * 256 + tid;
    int p = idx >> 7, d = idx & 127;
    int pos = p0 + p;
    float v;
    if (pos < 1024)
      v = cache_v[((size_t)(b * L_KV + pos) * HKV_N + h) * HD_N + d];
    else
      v = (float)vf[(size_t)(b * S_LEN + (pos - 1024)) * NKV + h * HD_N + d];
    T[d * 129 + p] = (half_t)v;
  }
  __syncthreads();
  #pragma unroll
  for (int i = 0; i < 64; ++i) {
    int idx = i * 256 + tid;
    int d = idx >> 7, p = idx & 127;
    vt[((size_t)(b * HKV_N + h) * HD_N + d) * L_KV + p0 + p] = T[d * 129 + p];
  }
}

// ---------------- flash attention: 4 waves/block, 16 q-rows/wave, KV tile 64 ----------------
__global__ __launch_bounds__(256) void attn_kernel(const half_t* __restrict__ qh,
                                                   const half_t* __restrict__ kh,
                                                   const half_t* __restrict__ vt,
                                                   half_t* __restrict__ ah) {
  __shared__ half_t Kt[64 * 128];                    // [key][d], XOR-swizzled
  __shared__ half_t Vt[128 * 64];                    // [d][key], XOR-swizzled
  __shared__ half_t Pl[4][16 * 72];                  // per-wave P: [q][key], pad 72
  const int tid = threadIdx.x;
  const int lane = tid & 63, w = tid >> 6;
  const int g = lane >> 4, qr = lane & 15;
  const int qt = blockIdx.x, hq = blockIdx.y, b = blockIdx.z;
  const int hkv = hq >> 2;
  const half_t* qbase =
      qh + ((size_t)((b * HQ_N + hq) * S_LEN) + qt * 64 + w * 16 + qr) * HD_N;
  half8 qf[4];
  #pragma unroll
  for (int c = 0; c < 4; ++c) qf[c] = *(const half8*)(qbase + g * 8 + c * 32);
  floatx4 acc[8] = {};
  float m_run = -1e30f, l_run = 0.f;
  const half_t* kg = kh + (size_t)(b * HKV_N + hkv) * L_KV * HD_N;
  const half_t* vg = vt + (size_t)(b * HKV_N + hkv) * HD_N * L_KV;
  for (int kt = 0; kt < L_KV / 64; ++kt) {
    __syncthreads();                                 // prior tile's reads done
    #pragma unroll
    for (int i = 0; i < 4; ++i) {                    // stage K tile [64 rows][128 cols]
      int ch = tid + 256 * i;                        // 1024 chunks of 8 halves
      int row = ch >> 4, c8 = ch & 15;               // 16 chunks per row
      int lb = (row * 256 + c8 * 16) ^ ((row & 7) << 4);
      *(uint4*)((char*)Kt + lb) =
          *(const uint4*)((const char*)(kg + (size_t)(kt * 64 + row) * HD_N) + c8 * 16);
    }
    #pragma unroll
    for (int i = 0; i < 4; ++i) {                    // stage V tile [128 rows][64 cols]
      int ch = tid + 256 * i;
      int d = ch >> 3, p8 = ch & 7;                  // 8 chunks per row
      int lb = (d * 128 + p8 * 16) ^ ((d & 7) << 4);
      *(uint4*)((char*)Vt + lb) =
          *(const uint4*)(vg + (size_t)d * L_KV + kt * 64 + p8 * 8);
    }
    __syncthreads();
    // swapped QK^T: T = K * Q^T  -> lane holds q-row (lane&15), keys ts*16+g*4+r
    float sc[16];
    #pragma unroll
    for (int ts = 0; ts < 4; ++ts) {
      floatx4 t = {0.f, 0.f, 0.f, 0.f};
      #pragma unroll
      for (int c = 0; c < 4; ++c) {
        int row = ts * 16 + qr;
        int lb = (row * 256 + (g * 8 + c * 32) * 2) ^ ((row & 7) << 4);
        half8 kfr = *(const half8*)((const char*)Kt + lb);
        t = __builtin_amdgcn_mfma_f32_16x16x32_f16(kfr, qf[c], t, 0, 0, 0);
      }
      sc[ts * 4 + 0] = t[0]; sc[ts * 4 + 1] = t[1];
      sc[ts * 4 + 2] = t[2]; sc[ts * 4 + 3] = t[3];
    }
    // online softmax for q = qr
    float pmax = sc[0];
    #pragma unroll
    for (int j = 1; j < 16; ++j) pmax = fmaxf(pmax, sc[j]);
    pmax = fmaxf(pmax, __shfl_xor(pmax, 16, 64));
    pmax = fmaxf(pmax, __shfl_xor(pmax, 32, 64));
    float mnew = fmaxf(m_run, pmax);
    float scale = __expf(m_run - mnew);
    float rs = 0.f;
    #pragma unroll
    for (int j = 0; j < 16; ++j) {
      float p = __expf(sc[j] - mnew);
      sc[j] = p;
      rs += p;
    }
    rs += __shfl_xor(rs, 16, 64);
    rs += __shfl_xor(rs, 32, 64);
    l_run = l_run * scale + rs;
    m_run = mnew;
    // P -> LDS (per-wave buffer; same-wave read, no barrier needed)
    #pragma unroll
    for (int ts = 0; ts < 4; ++ts) {
      half4v p4;
      p4[0] = (half_t)sc[ts * 4 + 0]; p4[1] = (half_t)sc[ts * 4 + 1];
      p4[2] = (half_t)sc[ts * 4 + 2]; p4[3] = (half_t)sc[ts * 4 + 3];
      *(half4v*)&Pl[w][qr * 72 + ts * 16 + g * 4] = p4;
    }
    // rescale accumulators; acc row r' = g*4+r
    float f0 = __shfl(scale, g * 4 + 0, 64);
    float f1 = __shfl(scale, g * 4 + 1, 64);
    float f2 = __shfl(scale, g * 4 + 2, 64);
    float f3 = __shfl(scale, g * 4 + 3, 64);
    #pragma unroll
    for (int n = 0; n < 8; ++n) {
      acc[n][0] *= f0; acc[n][1] *= f1; acc[n][2] *= f2; acc[n][3] *= f3;
    }
    // PV: out(16x128) += P(16x64) * V(64x128)
    #pragma unroll
    for (int kc = 0; kc < 2; ++kc) {
      half8 pf = *(const half8*)&Pl[w][qr * 72 + kc * 32 + g * 8];
      #pragma unroll
      for (int n = 0; n < 8; ++n) {
        int d = n * 16 + qr;
        int lb = (d * 128 + (kc * 32 + g * 8) * 2) ^ ((d & 7) << 4);
        half8 vfr = *(const half8*)((const char*)Vt + lb);
        acc[n] = __builtin_amdgcn_mfma_f32_16x16x32_f16(pf, vfr, acc[n], 0, 0, 0);
      }
    }
  }
  float il0 = 1.f / __shfl(l_run, g * 4 + 0, 64);
  float il1 = 1.f / __shfl(l_run, g * 4 + 1, 64);
  float il2 = 1.f / __shfl(l_run, g * 4 + 2, 64);
  float il3 = 1.f / __shfl(l_run, g * 4 + 3, 64);
  const int tokb = b * S_LEN + qt * 64 + w * 16 + g * 4;
  #pragma unroll
  for (int n = 0; n < 8; ++n) {
    const int col = hq * HD_N + n * 16 + qr;
    ah[(size_t)(tokb + 0) * DIM + col] = (half_t)(acc[n][0] * il0);
    ah[(size_t)(tokb + 1) * DIM + col] = (half_t)(acc[n][1] * il1);
    ah[(size_t)(tokb + 2) * DIM + col] = (half_t)(acc[n][2] * il2);
    ah[(size_t)(tokb + 3) * DIM + col] = (half_t)(acc[n][3] * il3);
  }
}

extern "C" void kernel_launch(void* const* d_in, const int* in_sizes, int n_in,
                              void* d_out, int out_size, void* d_ws, size_t ws_size,
                              hipStream_t stream) {
  (void)in_sizes; (void)n_in; (void)out_size; (void)ws_size;
  const float* x = (const float*)d_in[0];
  const float* wq = (const float*)d_in[1];
  const float* wk = (const float*)d_in[2];
  const float* wv = (const float*)d_in[3];
  const float* wo = (const float*)d_in[4];
  const float* fc = (const float*)d_in[5];
  const float* fs = (const float*)d_in[6];
  const float* ck = (const float*)d_in[7];
  const float* cv = (const float*)d_in[8];

  char* ws = (char*)d_ws;
  size_t off = 0;
  auto alloc = [&](size_t bytes) {
    char* p = ws + off;
    off += (bytes + 255) & ~(size_t)255;
    return p;
  };
  half_t* xh   = (half_t*)alloc((size_t)TOK * DIM * 2);      // later reused as qh
  half_t* wqT  = (half_t*)alloc((size_t)DIM * DIM * 2);
  half_t* wkT  = (half_t*)alloc((size_t)NKV * DIM * 2);
  half_t* wvT  = (half_t*)alloc((size_t)NKV * DIM * 2);
  half_t* qf16 = (half_t*)alloc((size_t)TOK * DIM * 2);      // later reused as ah
  half_t* kf16 = (half_t*)alloc((size_t)TOK * NKV * 2);
  half_t* vf16 = (half_t*)alloc((size_t)TOK * NKV * 2);
  half_t* kh   = (half_t*)alloc((size_t)B_SZ * HKV_N * L_KV * HD_N * 2);   // later woT (1st half)
  half_t* vth  = (half_t*)alloc((size_t)B_SZ * HKV_N * HD_N * L_KV * 2);   // later woT (2nd half)
  half_t* qh   = xh;    // alias: xh dead after the V GEMM
  half_t* ah   = qf16;  // alias: qf16 dead after pack_q
  half_t* woT  = kh;    // alias: kh+vth (contiguous 32MB) dead after attn

  // 1. convert x to f16
  conv_x_kernel<<<dim3(TOK * DIM / 4 / 256), dim3(256), 0, stream>>>(x, xh);
  // 2. weight transposes (f32 KxN -> f16 NxK)
  conv_transpose<<<dim3(DIM / 64, DIM / 64), dim3(256), 0, stream>>>(wq, wqT, DIM, DIM);
  conv_transpose<<<dim3(NKV / 64, DIM / 64), dim3(256), 0, stream>>>(wk, wkT, DIM, NKV);
  conv_transpose<<<dim3(NKV / 64, DIM / 64), dim3(256), 0, stream>>>(wv, wvT, DIM, NKV);
  // 3. QKV projections (f16 out)
  gemm_f16<half_t><<<dim3(DIM / 128, TOK / 128), dim3(256), 0, stream>>>(xh, wqT, qf16, TOK, DIM, DIM);
  gemm_f16<half_t><<<dim3(NKV / 128, TOK / 128), dim3(256), 0, stream>>>(xh, wkT, kf16, TOK, NKV, DIM);
  gemm_f16<half_t><<<dim3(NKV / 128, TOK / 128), dim3(256), 0, stream>>>(xh, wvT, vf16, TOK, NKV, DIM);
  // 4. rope + pack (xh no longer needed -> qh may overwrite it)
  pack_q_kernel<<<dim3(B_SZ * S_LEN * HQ_N * 64 / 256), dim3(256), 0, stream>>>(qf16, fc, fs, qh);
  pack_k_kernel<<<dim3(B_SZ * L_KV * HKV_N * 64 / 256), dim3(256), 0, stream>>>(kf16, ck, fc, fs, kh);
  pack_vt_kernel<<<dim3(B_SZ * HKV_N * (L_KV / 128)), dim3(256), 0, stream>>>(vf16, cv, vth);
  // 5. attention (writes ah = old qf16)
  attn_kernel<<<dim3(S_LEN / 64, HQ_N, B_SZ), dim3(256), 0, stream>>>(qh, kh, vth, ah);
  // 6. wo transpose (into kh+vth region, dead after attn), then output projection
  conv_transpose<<<dim3(DIM / 64, DIM / 64), dim3(256), 0, stream>>>(wo, woT, DIM, DIM);
  gemm_f16<float><<<dim3(DIM / 128, TOK / 128), dim3(256), 0, stream>>>(ah, woT, (float*)d_out, TOK, DIM, DIM);
}

// Round 3
// 722.696 us; speedup vs baseline: 1.3514x; 1.3514x over previous
//
#include <hip/hip_runtime.h>

typedef _Float16 half_t;
typedef _Float16 half8 __attribute__((ext_vector_type(8)));
typedef _Float16 half4v __attribute__((ext_vector_type(4)));
typedef _Float16 half2v __attribute__((ext_vector_type(2)));
typedef float floatx4 __attribute__((ext_vector_type(4)));

#define TOK 4096
#define DIM 4096
#define S_LEN 1024
#define B_SZ 4
#define HQ_N 32
#define HKV_N 8
#define HD_N 128
#define L_KV 2048
#define NKV 1024
#define NKV2 2048
#define QK_SCALE 0.08838834764831845f

__device__ __forceinline__ void gload_lds16(const void* g, void* l) {
  __builtin_amdgcn_global_load_lds(
      (const __attribute__((address_space(1))) unsigned int*)g,
      (__attribute__((address_space(3))) unsigned int*)l, 16, 0, 0);
}

// ---------------- elementwise f32 -> f16 ----------------
__global__ __launch_bounds__(256) void conv_x_kernel(const float* __restrict__ x,
                                                     half_t* __restrict__ xh) {
  int t = blockIdx.x * 256 + threadIdx.x;
  floatx4 v = *((const floatx4*)x + t);
  half4v o;
  o[0] = (half_t)v[0]; o[1] = (half_t)v[1]; o[2] = (half_t)v[2]; o[3] = (half_t)v[3];
  *((half4v*)xh + t) = o;
}

// ---------------- transpose + convert: out[n][k] = f16(in[k][n]) ----------------
__global__ __launch_bounds__(256) void conv_transpose(const float* __restrict__ in,
                                                      half_t* __restrict__ out,
                                                      int K, int N) {
  __shared__ half_t T[64 * 65];
  const int tid = threadIdx.x;
  const int n0 = blockIdx.x * 64, k0 = blockIdx.y * 64;
  #pragma unroll
  for (int i = 0; i < 16; ++i) {
    int idx = i * 256 + tid;
    int r = idx >> 6, c = idx & 63;
    T[c * 65 + r] = (half_t)in[(size_t)(k0 + r) * N + n0 + c];
  }
  __syncthreads();
  #pragma unroll
  for (int i = 0; i < 16; ++i) {
    int idx = i * 256 + tid;
    int rn = idx >> 6, ck = idx & 63;
    out[(size_t)(n0 + rn) * K + k0 + ck] = T[rn * 65 + ck];
  }
}

// ---------------- 128^2 GEMM (kept for kv projection): C = A * BT^T ----------------
template <typename OT>
__global__ __launch_bounds__(256) void gemm_f16(const half_t* __restrict__ A,
                                                const half_t* __restrict__ BT,
                                                OT* __restrict__ C,
                                                int M, int N, int K) {
  __shared__ half_t As[128 * 32];
  __shared__ half_t Bs[128 * 32];
  const int tid = threadIdx.x;
  const int lane = tid & 63;
  const int w = tid >> 6;
  const int wr = w >> 1, wc = w & 1;
  const int g = lane >> 4, qr = lane & 15;
  const int m0 = blockIdx.y * 128, n0 = blockIdx.x * 128;
  floatx4 acc[4][4] = {};
  const int chb0 = tid & 192;
  for (int k0 = 0; k0 < K; k0 += 32) {
    #pragma unroll
    for (int i = 0; i < 2; ++i) {
      int chb = chb0 + 256 * i;
      int ch = chb + lane;
      int row = ch >> 2, c8 = ch & 3;
      gload_lds16(A + (size_t)(m0 + row) * K + k0 + c8 * 8, (char*)As + chb * 16);
      gload_lds16(BT + (size_t)(n0 + row) * K + k0 + c8 * 8, (char*)Bs + chb * 16);
    }
    __syncthreads();
    half8 af[4], bf[4];
    const int koff = g * 8;
    #pragma unroll
    for (int m = 0; m < 4; ++m)
      af[m] = *(const half8*)&As[(wr * 64 + m * 16 + qr) * 32 + koff];
    #pragma unroll
    for (int n = 0; n < 4; ++n)
      bf[n] = *(const half8*)&Bs[(wc * 64 + n * 16 + qr) * 32 + koff];
    #pragma unroll
    for (int m = 0; m < 4; ++m)
      #pragma unroll
      for (int n = 0; n < 4; ++n)
        acc[m][n] = __builtin_amdgcn_mfma_f32_16x16x32_f16(af[m], bf[n], acc[m][n], 0, 0, 0);
    __syncthreads();
  }
  #pragma unroll
  for (int m = 0; m < 4; ++m) {
    int rb = m0 + wr * 64 + m * 16 + g * 4;
    #pragma unroll
    for (int n = 0; n < 4; ++n) {
      int col = n0 + wc * 64 + n * 16 + qr;
      #pragma unroll
      for (int r = 0; r < 4; ++r)
        C[(size_t)(rb + r) * N + col] = (OT)acc[m][n][r];
    }
  }
}

// ---------------- 256^2 8-phase GEMM (T1..T5): C[M][N] = A[M][K] * BT[N][K]^T ----------------
template <typename OT>
__global__ __launch_bounds__(512) void gemm256(const half_t* __restrict__ A,
                                               const half_t* __restrict__ BT,
                                               OT* __restrict__ C,
                                               int M, int N, int K) {
  __shared__ __align__(16) char smem[131072];   // A dbuf 64K | B dbuf 64K
  const int tid = threadIdx.x;
  const int lane = tid & 63, w = tid >> 6;
  const int g = lane >> 4, qr = lane & 15;
  const int wm = w >> 2, wn = w & 3;
  // XCD-aware bijective swizzle (grid % 8 == 0 for our shapes)
  const int nbx = N >> 8;
  const int nwg = gridDim.x;
  const int cpx = nwg >> 3;
  const int bid = ((int)blockIdx.x & 7) * cpx + ((int)blockIdx.x >> 3);
  const int bx = bid % nbx, by = bid / nbx;
  const int m0 = by << 8, n0 = bx << 8;
  const int NT = K >> 6;

  // staging precompute: half-tile = 128 rows x 64 cols f16; 1024 chunks of 16B; 2/thread
  const int ch0 = tid, ch1 = tid + 512;
  const int sr0 = ch0 >> 3, sc0 = (ch0 & 7) ^ (sr0 & 7);   // pre-swizzled source chunk
  const int sr1 = ch1 >> 3, sc1 = (ch1 & 7) ^ (sr1 & 7);
  const size_t so0 = (size_t)sr0 * K + sc0 * 8;
  const size_t so1 = (size_t)sr1 * K + sc1 * 8;
  const int wb = (w * 64) * 16;                             // wave-uniform LDS byte base
  const half_t* Ab = A + (size_t)m0 * K;
  const half_t* Bb = BT + (size_t)n0 * K;

#define G_STAGE(gsrc, ldst)                                   \
  do {                                                        \
    gload_lds16((gsrc) + so0, (char*)(ldst) + wb);            \
    gload_lds16((gsrc) + so1, (char*)(ldst) + wb + 8192);     \
  } while (0)

#define FRAG(base, row, kb) \
  (*(const half8*)((base) + ((((row) * 128) + (kb)) ^ (((row) & 7) << 4))))

  // prologue: tile0 all 4 halves -> buf0; tile1 A0,B0 -> buf1
  G_STAGE(Ab, smem);                               // t0.A0
  G_STAGE(Ab + (size_t)128 * K, smem + 16384);     // t0.A1
  G_STAGE(Bb, smem + 65536);                       // t0.B0
  G_STAGE(Bb + (size_t)128 * K, smem + 81920);     // t0.B1
  G_STAGE(Ab + 64, smem + 32768);                  // t1.A0
  G_STAGE(Bb + 64, smem + 98304);                  // t1.B0
  asm volatile("s_waitcnt vmcnt(4)" ::: "memory");
  __builtin_amdgcn_s_barrier();

  floatx4 acc[8][4] = {};
  half8 aF[4][2], bF0[2][2], bF1[2][2];

#define MFMA_Q(mh, nh, BF)                                                     \
  do {                                                                         \
    __builtin_amdgcn_s_setprio(1);                                             \
    _Pragma("unroll") for (int mf = 0; mf < 4; ++mf)                           \
    _Pragma("unroll") for (int nf = 0; nf < 2; ++nf)                           \
    _Pragma("unroll") for (int kk = 0; kk < 2; ++kk)                           \
      acc[(mh)*4 + mf][(nh)*2 + nf] = __builtin_amdgcn_mfma_f32_16x16x32_f16(  \
          aF[mf][kk], BF[nf][kk], acc[(mh)*4 + mf][(nh)*2 + nf], 0, 0, 0);     \
    __builtin_amdgcn_s_setprio(0);                                             \
  } while (0)

  for (int t = 0; t < NT; ++t) {
    const char* Ac = smem + ((t & 1) ? 32768 : 0);
    const char* Bc = smem + 65536 + ((t & 1) ? 32768 : 0);
    char* An = smem + ((t & 1) ? 0 : 32768);
    char* Bn = smem + 65536 + ((t & 1) ? 0 : 32768);
    const int t1 = (t + 1 < NT) ? t + 1 : NT - 1;
    const int t2 = (t + 2 < NT) ? t + 2 : NT - 1;
    // ---- phase 0: read A(mh=0), B(nh=0); stage (t+1).A1 -> other buf
    #pragma unroll
    for (int mf = 0; mf < 4; ++mf)
      #pragma unroll
      for (int kk = 0; kk < 2; ++kk)
        aF[mf][kk] = FRAG(Ac, wm * 128 + mf * 16 + qr, kk * 64 + g * 16);
    #pragma unroll
    for (int nf = 0; nf < 2; ++nf)
      #pragma unroll
      for (int kk = 0; kk < 2; ++kk)
        bF0[nf][kk] = FRAG(Bc, wn * 64 + nf * 16 + qr, kk * 64 + g * 16);
    G_STAGE(Ab + (size_t)128 * K + t1 * 64, An + 16384);
    __builtin_amdgcn_s_barrier();
    asm volatile("s_waitcnt lgkmcnt(0)" ::: "memory");
    MFMA_Q(0, 0, bF0);
    __builtin_amdgcn_s_barrier();
    // ---- phase 1: read B(nh=1); stage (t+1).B1 -> other buf
    #pragma unroll
    for (int nf = 0; nf < 2; ++nf)
      #pragma unroll
      for (int kk = 0; kk < 2; ++kk)
        bF1[nf][kk] = FRAG(Bc, wn * 64 + 32 + nf * 16 + qr, kk * 64 + g * 16);
    G_STAGE(Bb + (size_t)128 * K + t1 * 64, Bn + 16384);
    __builtin_amdgcn_s_barrier();
    asm volatile("s_waitcnt lgkmcnt(0)" ::: "memory");
    MFMA_Q(0, 1, bF1);
    __builtin_amdgcn_s_barrier();
    // ---- phase 2: read A(mh=1)
    #pragma unroll
    for (int mf = 0; mf < 4; ++mf)
      #pragma unroll
      for (int kk = 0; kk < 2; ++kk)
        aF[mf][kk] = FRAG(Ac, wm * 128 + 64 + mf * 16 + qr, kk * 64 + g * 16);
    __builtin_amdgcn_s_barrier();
    asm volatile("s_waitcnt lgkmcnt(0)" ::: "memory");
    MFMA_Q(1, 1, bF1);
    __builtin_amdgcn_s_barrier();
    // ---- phase 3: stage (t+2).A0/B0 into cur-parity buf (regions fully read); counted vmcnt
    G_STAGE(Ab + (size_t)t2 * 64, (char*)Ac);
    G_STAGE(Bb + (size_t)t2 * 64, (char*)Bc);
    __builtin_amdgcn_s_barrier();
    MFMA_Q(1, 0, bF0);
    asm volatile("s_waitcnt vmcnt(4)" ::: "memory");
    __builtin_amdgcn_s_barrier();
  }
  // epilogue
  #pragma unroll
  for (int mh = 0; mh < 2; ++mh)
    #pragma unroll
    for (int mf = 0; mf < 4; ++mf) {
      const int rb = m0 + wm * 128 + mh * 64 + mf * 16 + g * 4;
      #pragma unroll
      for (int nh = 0; nh < 2; ++nh)
        #pragma unroll
        for (int nf = 0; nf < 2; ++nf) {
          const int col = n0 + wn * 64 + nh * 32 + nf * 16 + qr;
          floatx4 v = acc[mh * 4 + mf][nh * 2 + nf];
          #pragma unroll
          for (int r = 0; r < 4; ++r)
            C[(size_t)(rb + r) * N + col] = (OT)v[r];
        }
    }
#undef G_STAGE
#undef FRAG
#undef MFMA_Q
}

// ---------------- pack q: rope + scale -> [B][HQ][S][HD] f16 ----------------
__global__ __launch_bounds__(256) void pack_q_kernel(const half_t* __restrict__ qf,
                                                     const float* __restrict__ cosT,
                                                     const float* __restrict__ sinT,
                                                     half_t* __restrict__ qh) {
  int t = blockIdx.x * 256 + threadIdx.x;
  int j = t & 63;
  int hq = (t >> 6) & 31;
  int tok = t >> 11;
  int s = tok & 1023;
  int b = tok >> 10;
  const half_t* src = qf + (size_t)tok * DIM + hq * HD_N + 2 * j;
  float xr = (float)src[0], xi = (float)src[1];
  float c = cosT[s * 64 + j], sn = sinT[s * 64 + j];
  half2v o;
  o[0] = (half_t)((xr * c - xi * sn) * QK_SCALE);
  o[1] = (half_t)((xr * sn + xi * c) * QK_SCALE);
  *(half2v*)(qh + ((size_t)((b * HQ_N + hq) * S_LEN + s)) * HD_N + 2 * j) = o;
}

// ---------------- pack keys from fused kv: cache + rope(new) -> [B][HKV][L][HD] f16 ----------------
__global__ __launch_bounds__(256) void pack_k_kernel(const half_t* __restrict__ kvf,
                                                     const float* __restrict__ cache_k,
                                                     const float* __restrict__ cosT,
                                                     const float* __restrict__ sinT,
                                                     half_t* __restrict__ kh) {
  int t = blockIdx.x * 256 + threadIdx.x;
  int j = t & 63;
  int h = (t >> 6) & 7;
  int pos = (t >> 9) & 2047;
  int b = t >> 20;
  float xr, xi;
  if (pos < 1024) {
    const float* src = cache_k + ((size_t)(b * L_KV + pos) * HKV_N + h) * HD_N + 2 * j;
    xr = src[0]; xi = src[1];
  } else {
    int s = pos - 1024;
    const half_t* src = kvf + (size_t)(b * S_LEN + s) * NKV2 + h * HD_N + 2 * j;
    float r0 = (float)src[0], i0 = (float)src[1];
    float c = cosT[s * 64 + j], sn = sinT[s * 64 + j];
    xr = r0 * c - i0 * sn;
    xi = r0 * sn + i0 * c;
  }
  half2v o; o[0] = (half_t)xr; o[1] = (half_t)xi;
  *(half2v*)(kh + ((size_t)(b * HKV_N + h) * L_KV + pos) * HD_N + 2 * j) = o;
}

// ---------------- pack values transposed from fused kv: -> [B][HKV][HD][L] f16 ----------------
__global__ __launch_bounds__(256) void pack_vt_kernel(const half_t* __restrict__ kvf,
                                                      const float* __restrict__ cache_v,
                                                      half_t* __restrict__ vt) {
  __shared__ half_t T[128 * 129];
  const int tid = threadIdx.x;
  const int blk = blockIdx.x;
  const int pt = blk & 15;
  const int h = (blk >> 4) & 7;
  const int b = blk >> 7;
  const int p0 = pt * 128;
  #pragma unroll
  for (int i = 0; i < 64; ++i) {
    int idx = i * 256 + tid;
    int p = idx >> 7, d = idx & 127;
    int pos = p0 + p;
    float v;
    if (pos < 1024)
      v = cache_v[((size_t)(b * L_KV + pos) * HKV_N + h) * HD_N + d];
    else
      v = (float)kvf[(size_t)(b * S_LEN + (pos - 1024)) * NKV2 + NKV + h * HD_N + d];
    T[d * 129 + p] = (half_t)v;
  }
  __syncthreads();
  #pragma unroll
  for (int i = 0; i < 64; ++i) {
    int idx = i * 256 + tid;
    int d = idx >> 7, p = idx & 127;
    vt[((size_t)(b * HKV_N + h) * HD_N + d) * L_KV + p0 + p] = T[d * 129 + p];
  }
}

// ---------------- flash attention: dbuf gload_lds staging, defer-max, setprio ----------------
__global__ __launch_bounds__(256) void attn_kernel(const half_t* __restrict__ qh,
                                                   const half_t* __restrict__ kh,
                                                   const half_t* __restrict__ vt,
                                                   half_t* __restrict__ ah) {
  __shared__ __align__(16) half_t K2[2][64 * 128];   // [key][d], XOR-swizzled (logical)
  __shared__ __align__(16) half_t V2[2][128 * 64];   // [d][key], XOR-swizzled (logical)
  __shared__ __align__(16) half_t Pl[4][16 * 72];    // per-wave P: [q][key], pad 72
  const int tid = threadIdx.x;
  const int lane = tid & 63, w = tid >> 6;
  const int g = lane >> 4, qr = lane & 15;
  const int qt = blockIdx.x, hq = blockIdx.y, b = blockIdx.z;
  const int hkv = hq >> 2;
  const half_t* qbase =
      qh + ((size_t)((b * HQ_N + hq) * S_LEN) + qt * 64 + w * 16 + qr) * HD_N;
  half8 qf[4];
  #pragma unroll
  for (int c = 0; c < 4; ++c) qf[c] = *(const half8*)(qbase + g * 8 + c * 32);
  floatx4 acc[8] = {};
  float m_run = -1e30f, l_run = 0.f;
  const half_t* kg = kh + (size_t)(b * HKV_N + hkv) * L_KV * HD_N;
  const half_t* vg = vt + (size_t)(b * HKV_N + hkv) * HD_N * L_KV;

  // staging: pre-swizzled global source, linear LDS dest (rule 21)
#define STAGE_KV(kt, kb)                                                        \
  do {                                                                          \
    _Pragma("unroll") for (int i = 0; i < 4; ++i) {                             \
      int ch = tid + 256 * i;                                                   \
      int row = ch >> 4;                                                        \
      int c8 = (ch & 15) ^ (row & 7);                                           \
      gload_lds16(kg + (size_t)((kt)*64 + row) * HD_N + c8 * 8,                 \
                  (char*)K2[kb] + (tid & ~63) * 16 + i * 4096);                 \
    }                                                                           \
    _Pragma("unroll") for (int i = 0; i < 4; ++i) {                             \
      int ch = tid + 256 * i;                                                   \
      int d = ch >> 3;                                                          \
      int p8 = (ch & 7) ^ (d & 7);                                              \
      gload_lds16(vg + (size_t)d * L_KV + (kt)*64 + p8 * 8,                     \
                  (char*)V2[kb] + (tid & ~63) * 16 + i * 4096);                 \
    }                                                                           \
  } while (0)

  STAGE_KV(0, 0);
  asm volatile("s_waitcnt vmcnt(0)" ::: "memory");
  __builtin_amdgcn_s_barrier();

  for (int kt = 0; kt < L_KV / 64; ++kt) {
    const int cb = kt & 1;
    if (kt + 1 < L_KV / 64) STAGE_KV(kt + 1, cb ^ 1);   // prefetch next tile (async)
    const char* Kt = (const char*)K2[cb];
    const char* Vt = (const char*)V2[cb];
    // swapped QK^T: lane holds q-row (lane&15), keys ts*16+g*4+r
    float sc[16];
    __builtin_amdgcn_s_setprio(1);
    #pragma unroll
    for (int ts = 0; ts < 4; ++ts) {
      floatx4 tq = {0.f, 0.f, 0.f, 0.f};
      #pragma unroll
      for (int c = 0; c < 4; ++c) {
        int row = ts * 16 + qr;
        int lb = (row * 256 + (g * 8 + c * 32) * 2) ^ ((row & 7) << 4);
        half8 kfr = *(const half8*)(Kt + lb);
        tq = __builtin_amdgcn_mfma_f32_16x16x32_f16(kfr, qf[c], tq, 0, 0, 0);
      }
      sc[ts * 4 + 0] = tq[0]; sc[ts * 4 + 1] = tq[1];
      sc[ts * 4 + 2] = tq[2]; sc[ts * 4 + 3] = tq[3];
    }
    __builtin_amdgcn_s_setprio(0);
    // online softmax with defer-max (T13, THR=8)
    float pmax = sc[0];
    #pragma unroll
    for (int j = 1; j < 16; ++j) pmax = fmaxf(pmax, sc[j]);
    pmax = fmaxf(pmax, __shfl_xor(pmax, 16, 64));
    pmax = fmaxf(pmax, __shfl_xor(pmax, 32, 64));
    const bool skip = __all(pmax - m_run <= 8.f);
    float mnew = skip ? m_run : fmaxf(m_run, pmax);
    float rs = 0.f;
    #pragma unroll
    for (int j = 0; j < 16; ++j) {
      float p = __expf(sc[j] - mnew);
      sc[j] = p;
      rs += p;
    }
    rs += __shfl_xor(rs, 16, 64);
    rs += __shfl_xor(rs, 32, 64);
    if (skip) {
      l_run += rs;
    } else {
      float scale = __expf(m_run - mnew);
      l_run = l_run * scale + rs;
      float f0 = __shfl(scale, g * 4 + 0, 64);
      float f1 = __shfl(scale, g * 4 + 1, 64);
      float f2 = __shfl(scale, g * 4 + 2, 64);
      float f3 = __shfl(scale, g * 4 + 3, 64);
      #pragma unroll
      for (int n = 0; n < 8; ++n) {
        acc[n][0] *= f0; acc[n][1] *= f1; acc[n][2] *= f2; acc[n][3] *= f3;
      }
      m_run = mnew;
    }
    // P -> per-wave LDS buffer (same-wave read, no barrier needed)
    #pragma unroll
    for (int ts = 0; ts < 4; ++ts) {
      half4v p4;
      p4[0] = (half_t)sc[ts * 4 + 0]; p4[1] = (half_t)sc[ts * 4 + 1];
      p4[2] = (half_t)sc[ts * 4 + 2]; p4[3] = (half_t)sc[ts * 4 + 3];
      *(half4v*)&Pl[w][qr * 72 + ts * 16 + g * 4] = p4;
    }
    // PV: out(16x128) += P(16x64) * V(64x128)
    __builtin_amdgcn_s_setprio(1);
    #pragma unroll
    for (int kc = 0; kc < 2; ++kc) {
      half8 pf = *(const half8*)&Pl[w][qr * 72 + kc * 32 + g * 8];
      #pragma unroll
      for (int n = 0; n < 8; ++n) {
        int d = n * 16 + qr;
        int lb = (d * 128 + (kc * 32 + g * 8) * 2) ^ ((d & 7) << 4);
        half8 vfr = *(const half8*)(Vt + lb);
        acc[n] = __builtin_amdgcn_mfma_f32_16x16x32_f16(pf, vfr, acc[n], 0, 0, 0);
      }
    }
    __builtin_amdgcn_s_setprio(0);
    asm volatile("s_waitcnt vmcnt(0)" ::: "memory");  // prefetch landed (hidden under compute)
    __builtin_amdgcn_s_barrier();
  }
  float il0 = 1.f / __shfl(l_run, g * 4 + 0, 64);
  float il1 = 1.f / __shfl(l_run, g * 4 + 1, 64);
  float il2 = 1.f / __shfl(l_run, g * 4 + 2, 64);
  float il3 = 1.f / __shfl(l_run, g * 4 + 3, 64);
  const int tokb = b * S_LEN + qt * 64 + w * 16 + g * 4;
  #pragma unroll
  for (int n = 0; n < 8; ++n) {
    const int col = hq * HD_N + n * 16 + qr;
    ah[(size_t)(tokb + 0) * DIM + col] = (half_t)(acc[n][0] * il0);
    ah[(size_t)(tokb + 1) * DIM + col] = (half_t)(acc[n][1] * il1);
    ah[(size_t)(tokb + 2) * DIM + col] = (half_t)(acc[n][2] * il2);
    ah[(size_t)(tokb + 3) * DIM + col] = (half_t)(acc[n][3] * il3);
  }
#undef STAGE_KV
}

extern "C" void kernel_launch(void* const* d_in, const int* in_sizes, int n_in,
                              void* d_out, int out_size, void* d_ws, size_t ws_size,
                              hipStream_t stream) {
  (void)in_sizes; (void)n_in; (void)out_size; (void)ws_size;
  const float* x = (const float*)d_in[0];
  const float* wq = (const float*)d_in[1];
  const float* wk = (const float*)d_in[2];
  const float* wv = (const float*)d_in[3];
  const float* wo = (const float*)d_in[4];
  const float* fc = (const float*)d_in[5];
  const float* fs = (const float*)d_in[6];
  const float* ck = (const float*)d_in[7];
  const float* cv = (const float*)d_in[8];

  char* ws = (char*)d_ws;
  size_t off = 0;
  auto alloc = [&](size_t bytes) {
    char* p = ws + off;
    off += (bytes + 255) & ~(size_t)255;
    return p;
  };
  half_t* xh    = (half_t*)alloc((size_t)TOK * DIM * 2);        // reused as qh
  half_t* wqT   = (half_t*)alloc((size_t)DIM * DIM * 2);
  half_t* kvT   = (half_t*)alloc((size_t)NKV2 * DIM * 2);       // wk^T | wv^T; + next = woT
  half_t* kvf16 = (half_t*)alloc((size_t)TOK * NKV2 * 2);
  half_t* qf16  = (half_t*)alloc((size_t)TOK * DIM * 2);        // reused as ah
  half_t* kh    = (half_t*)alloc((size_t)B_SZ * HKV_N * L_KV * HD_N * 2);
  half_t* vth   = (half_t*)alloc((size_t)B_SZ * HKV_N * HD_N * L_KV * 2);
  half_t* qh    = xh;    // alias: xh dead after kv GEMM
  half_t* ah    = qf16;  // alias: qf16 dead after pack_q
  half_t* woT   = kvT;   // alias: kvT+kvf16 (contiguous 32MB) dead after attn

  // 1. convert x to f16
  conv_x_kernel<<<dim3(TOK * DIM / 4 / 256), dim3(256), 0, stream>>>(x, xh);
  // 2. weight transposes (f32 KxN -> f16 NxK)
  conv_transpose<<<dim3(DIM / 64, DIM / 64), dim3(256), 0, stream>>>(wq, wqT, DIM, DIM);
  conv_transpose<<<dim3(NKV / 64, DIM / 64), dim3(256), 0, stream>>>(wk, kvT, DIM, NKV);
  conv_transpose<<<dim3(NKV / 64, DIM / 64), dim3(256), 0, stream>>>(wv, kvT + (size_t)NKV * DIM, DIM, NKV);
  // 3. projections: q via 8-phase 256^2; fused kv via 128^2
  gemm256<half_t><<<dim3((TOK / 256) * (DIM / 256)), dim3(512), 0, stream>>>(xh, wqT, qf16, TOK, DIM, DIM);
  gemm_f16<half_t><<<dim3(NKV2 / 128, TOK / 128), dim3(256), 0, stream>>>(xh, kvT, kvf16, TOK, NKV2, DIM);
  // 4. rope + pack (xh no longer needed -> qh may overwrite it)
  pack_q_kernel<<<dim3(B_SZ * S_LEN * HQ_N * 64 / 256), dim3(256), 0, stream>>>(qf16, fc, fs, qh);
  pack_k_kernel<<<dim3(B_SZ * L_KV * HKV_N * 64 / 256), dim3(256), 0, stream>>>(kvf16, ck, fc, fs, kh);
  pack_vt_kernel<<<dim3(B_SZ * HKV_N * (L_KV / 128)), dim3(256), 0, stream>>>(kvf16, cv, vth);
  // 5. attention (writes ah = old qf16)
  attn_kernel<<<dim3(S_LEN / 64, HQ_N, B_SZ), dim3(256), 0, stream>>>(qh, kh, vth, ah);
  // 6. wo transpose (into kvT+kvf16 region, dead after attn), then output projection
  conv_transpose<<<dim3(DIM / 64, DIM / 64), dim3(256), 0, stream>>>(wo, woT, DIM, DIM);
  gemm256<float><<<dim3((TOK / 256) * (DIM / 256)), dim3(512), 0, stream>>>(ah, woT, (float*)d_out, TOK, DIM, DIM);
}

// Round 4
// 701.730 us; speedup vs baseline: 1.3918x; 1.0299x over previous
//
#include <hip/hip_runtime.h>

typedef _Float16 half_t;
typedef _Float16 half8 __attribute__((ext_vector_type(8)));
typedef _Float16 half4v __attribute__((ext_vector_type(4)));
typedef _Float16 half2v __attribute__((ext_vector_type(2)));
typedef float floatx4 __attribute__((ext_vector_type(4)));

#define TOK 4096
#define DIM 4096
#define S_LEN 1024
#define B_SZ 4
#define HQ_N 32
#define HKV_N 8
#define HD_N 128
#define L_KV 2048
#define NKV 1024
#define NQKV 6144
#define QK_SCALE 0.08838834764831845f
#define LOG2E 1.4426950408889634f

__device__ __forceinline__ void gload_lds16(const void* g, void* l) {
  __builtin_amdgcn_global_load_lds(
      (const __attribute__((address_space(1))) unsigned int*)g,
      (__attribute__((address_space(3))) unsigned int*)l, 16, 0, 0);
}

__device__ __forceinline__ float max3f(float a, float b, float c) {
  return fmaxf(fmaxf(a, b), c);   // fuses to v_max3_f32
}

// ---------------- elementwise f32 -> f16 ----------------
__global__ __launch_bounds__(256) void conv_x_kernel(const float* __restrict__ x,
                                                     half_t* __restrict__ xh) {
  int t = blockIdx.x * 256 + threadIdx.x;
  floatx4 v = *((const floatx4*)x + t);
  half4v o;
  o[0] = (half_t)v[0]; o[1] = (half_t)v[1]; o[2] = (half_t)v[2]; o[3] = (half_t)v[3];
  *((half4v*)xh + t) = o;
}

// ---------------- transpose + convert: out[n][k] = f16(in[k][n]) ----------------
__global__ __launch_bounds__(256) void conv_transpose(const float* __restrict__ in,
                                                      half_t* __restrict__ out,
                                                      int K, int N) {
  __shared__ half_t T[64 * 65];
  const int tid = threadIdx.x;
  const int n0 = blockIdx.x * 64, k0 = blockIdx.y * 64;
  #pragma unroll
  for (int i = 0; i < 16; ++i) {
    int idx = i * 256 + tid;
    int r = idx >> 6, c = idx & 63;
    T[c * 65 + r] = (half_t)in[(size_t)(k0 + r) * N + n0 + c];
  }
  __syncthreads();
  #pragma unroll
  for (int i = 0; i < 16; ++i) {
    int idx = i * 256 + tid;
    int rn = idx >> 6, ck = idx & 63;
    out[(size_t)(n0 + rn) * K + k0 + ck] = T[rn * 65 + ck];
  }
}

// ---------------- 256^2 8-phase GEMM (T1..T5): C[M][N] = A[M][K] * BT[N][K]^T ----------------
template <typename OT>
__global__ __launch_bounds__(512) void gemm256(const half_t* __restrict__ A,
                                               const half_t* __restrict__ BT,
                                               OT* __restrict__ C,
                                               int M, int N, int K) {
  __shared__ __align__(16) char smem[131072];   // A dbuf 64K | B dbuf 64K
  const int tid = threadIdx.x;
  const int lane = tid & 63, w = tid >> 6;
  const int g = lane >> 4, qr = lane & 15;
  const int wm = w >> 2, wn = w & 3;
  const int nbx = N >> 8;
  const int nwg = gridDim.x;
  const int cpx = nwg >> 3;
  const int bid = ((int)blockIdx.x & 7) * cpx + ((int)blockIdx.x >> 3);
  const int bx = bid % nbx, by = bid / nbx;
  const int m0 = by << 8, n0 = bx << 8;
  const int NT = K >> 6;

  const int ch0 = tid, ch1 = tid + 512;
  const int sr0 = ch0 >> 3, sc0 = (ch0 & 7) ^ (sr0 & 7);
  const int sr1 = ch1 >> 3, sc1 = (ch1 & 7) ^ (sr1 & 7);
  const size_t so0 = (size_t)sr0 * K + sc0 * 8;
  const size_t so1 = (size_t)sr1 * K + sc1 * 8;
  const int wb = (w * 64) * 16;
  const half_t* Ab = A + (size_t)m0 * K;
  const half_t* Bb = BT + (size_t)n0 * K;

#define G_STAGE(gsrc, ldst)                                   \
  do {                                                        \
    gload_lds16((gsrc) + so0, (char*)(ldst) + wb);            \
    gload_lds16((gsrc) + so1, (char*)(ldst) + wb + 8192);     \
  } while (0)

#define FRAG(base, row, kb) \
  (*(const half8*)((base) + ((((row) * 128) + (kb)) ^ (((row) & 7) << 4))))

  G_STAGE(Ab, smem);
  G_STAGE(Ab + (size_t)128 * K, smem + 16384);
  G_STAGE(Bb, smem + 65536);
  G_STAGE(Bb + (size_t)128 * K, smem + 81920);
  G_STAGE(Ab + 64, smem + 32768);
  G_STAGE(Bb + 64, smem + 98304);
  asm volatile("s_waitcnt vmcnt(4)" ::: "memory");
  __builtin_amdgcn_s_barrier();

  floatx4 acc[8][4] = {};
  half8 aF[4][2], bF0[2][2], bF1[2][2];

#define MFMA_Q(mh, nh, BF)                                                     \
  do {                                                                         \
    __builtin_amdgcn_s_setprio(1);                                             \
    _Pragma("unroll") for (int mf = 0; mf < 4; ++mf)                           \
    _Pragma("unroll") for (int nf = 0; nf < 2; ++nf)                           \
    _Pragma("unroll") for (int kk = 0; kk < 2; ++kk)                           \
      acc[(mh)*4 + mf][(nh)*2 + nf] = __builtin_amdgcn_mfma_f32_16x16x32_f16(  \
          aF[mf][kk], BF[nf][kk], acc[(mh)*4 + mf][(nh)*2 + nf], 0, 0, 0);     \
    __builtin_amdgcn_s_setprio(0);                                             \
  } while (0)

  for (int t = 0; t < NT; ++t) {
    const char* Ac = smem + ((t & 1) ? 32768 : 0);
    const char* Bc = smem + 65536 + ((t & 1) ? 32768 : 0);
    char* An = smem + ((t & 1) ? 0 : 32768);
    char* Bn = smem + 65536 + ((t & 1) ? 0 : 32768);
    const int t1 = (t + 1 < NT) ? t + 1 : NT - 1;
    const int t2 = (t + 2 < NT) ? t + 2 : NT - 1;
    // phase 0
    #pragma unroll
    for (int mf = 0; mf < 4; ++mf)
      #pragma unroll
      for (int kk = 0; kk < 2; ++kk)
        aF[mf][kk] = FRAG(Ac, wm * 128 + mf * 16 + qr, kk * 64 + g * 16);
    #pragma unroll
    for (int nf = 0; nf < 2; ++nf)
      #pragma unroll
      for (int kk = 0; kk < 2; ++kk)
        bF0[nf][kk] = FRAG(Bc, wn * 64 + nf * 16 + qr, kk * 64 + g * 16);
    G_STAGE(Ab + (size_t)128 * K + t1 * 64, An + 16384);
    __builtin_amdgcn_s_barrier();
    asm volatile("s_waitcnt lgkmcnt(0)" ::: "memory");
    MFMA_Q(0, 0, bF0);
    __builtin_amdgcn_s_barrier();
    // phase 1
    #pragma unroll
    for (int nf = 0; nf < 2; ++nf)
      #pragma unroll
      for (int kk = 0; kk < 2; ++kk)
        bF1[nf][kk] = FRAG(Bc, wn * 64 + 32 + nf * 16 + qr, kk * 64 + g * 16);
    G_STAGE(Bb + (size_t)128 * K + t1 * 64, Bn + 16384);
    __builtin_amdgcn_s_barrier();
    asm volatile("s_waitcnt lgkmcnt(0)" ::: "memory");
    MFMA_Q(0, 1, bF1);
    __builtin_amdgcn_s_barrier();
    // phase 2
    #pragma unroll
    for (int mf = 0; mf < 4; ++mf)
      #pragma unroll
      for (int kk = 0; kk < 2; ++kk)
        aF[mf][kk] = FRAG(Ac, wm * 128 + 64 + mf * 16 + qr, kk * 64 + g * 16);
    __builtin_amdgcn_s_barrier();
    asm volatile("s_waitcnt lgkmcnt(0)" ::: "memory");
    MFMA_Q(1, 1, bF1);
    __builtin_amdgcn_s_barrier();
    // phase 3
    G_STAGE(Ab + (size_t)t2 * 64, (char*)Ac);
    G_STAGE(Bb + (size_t)t2 * 64, (char*)Bc);
    __builtin_amdgcn_s_barrier();
    MFMA_Q(1, 0, bF0);
    asm volatile("s_waitcnt vmcnt(4)" ::: "memory");
    __builtin_amdgcn_s_barrier();
  }
  #pragma unroll
  for (int mh = 0; mh < 2; ++mh)
    #pragma unroll
    for (int mf = 0; mf < 4; ++mf) {
      const int rb = m0 + wm * 128 + mh * 64 + mf * 16 + g * 4;
      #pragma unroll
      for (int nh = 0; nh < 2; ++nh)
        #pragma unroll
        for (int nf = 0; nf < 2; ++nf) {
          const int col = n0 + wn * 64 + nh * 32 + nf * 16 + qr;
          floatx4 v = acc[mh * 4 + mf][nh * 2 + nf];
          #pragma unroll
          for (int r = 0; r < 4; ++r)
            C[(size_t)(rb + r) * N + col] = (OT)v[r];
        }
    }
#undef G_STAGE
#undef FRAG
#undef MFMA_Q
}

// ---------------- pack q: rope + scale*log2e -> [B][HQ][S][HD] f16 ----------------
__global__ __launch_bounds__(256) void pack_q_kernel(const half_t* __restrict__ qkv,
                                                     const float* __restrict__ cosT,
                                                     const float* __restrict__ sinT,
                                                     half_t* __restrict__ qh) {
  int t = blockIdx.x * 256 + threadIdx.x;
  int j = t & 63;
  int hq = (t >> 6) & 31;
  int tok = t >> 11;
  int s = tok & 1023;
  int b = tok >> 10;
  const half_t* src = qkv + (size_t)tok * NQKV + hq * HD_N + 2 * j;
  float xr = (float)src[0], xi = (float)src[1];
  float c = cosT[s * 64 + j], sn = sinT[s * 64 + j];
  const float QS2 = QK_SCALE * LOG2E;   // exp2-domain scores
  half2v o;
  o[0] = (half_t)((xr * c - xi * sn) * QS2);
  o[1] = (half_t)((xr * sn + xi * c) * QS2);
  *(half2v*)(qh + ((size_t)((b * HQ_N + hq) * S_LEN + s)) * HD_N + 2 * j) = o;
}

// ---------------- pack keys: cache + rope(new) -> [B][HKV][L][HD] f16 ----------------
__global__ __launch_bounds__(256) void pack_k_kernel(const half_t* __restrict__ qkv,
                                                     const float* __restrict__ cache_k,
                                                     const float* __restrict__ cosT,
                                                     const float* __restrict__ sinT,
                                                     half_t* __restrict__ kh) {
  int t = blockIdx.x * 256 + threadIdx.x;
  int j = t & 63;
  int h = (t >> 6) & 7;
  int pos = (t >> 9) & 2047;
  int b = t >> 20;
  float xr, xi;
  if (pos < 1024) {
    const float* src = cache_k + ((size_t)(b * L_KV + pos) * HKV_N + h) * HD_N + 2 * j;
    xr = src[0]; xi = src[1];
  } else {
    int s = pos - 1024;
    const half_t* src = qkv + (size_t)(b * S_LEN + s) * NQKV + DIM + h * HD_N + 2 * j;
    float r0 = (float)src[0], i0 = (float)src[1];
    float c = cosT[s * 64 + j], sn = sinT[s * 64 + j];
    xr = r0 * c - i0 * sn;
    xi = r0 * sn + i0 * c;
  }
  half2v o; o[0] = (half_t)xr; o[1] = (half_t)xi;
  *(half2v*)(kh + ((size_t)(b * HKV_N + h) * L_KV + pos) * HD_N + 2 * j) = o;
}

// ---------------- pack values transposed: -> [B][HKV][HD][L] f16 ----------------
__global__ __launch_bounds__(256) void pack_vt_kernel(const half_t* __restrict__ qkv,
                                                      const float* __restrict__ cache_v,
                                                      half_t* __restrict__ vt) {
  __shared__ half_t T[128 * 129];
  const int tid = threadIdx.x;
  const int blk = blockIdx.x;
  const int pt = blk & 15;
  const int h = (blk >> 4) & 7;
  const int b = blk >> 7;
  const int p0 = pt * 128;
  #pragma unroll
  for (int i = 0; i < 64; ++i) {
    int idx = i * 256 + tid;
    int p = idx >> 7, d = idx & 127;
    int pos = p0 + p;
    float v;
    if (pos < 1024)
      v = cache_v[((size_t)(b * L_KV + pos) * HKV_N + h) * HD_N + d];
    else
      v = (float)qkv[(size_t)(b * S_LEN + (pos - 1024)) * NQKV + DIM + NKV + h * HD_N + d];
    T[d * 129 + p] = (half_t)v;
  }
  __syncthreads();
  #pragma unroll
  for (int i = 0; i < 64; ++i) {
    int idx = i * 256 + tid;
    int d = idx >> 7, p = idx & 127;
    vt[((size_t)(b * HKV_N + h) * HD_N + d) * L_KV + p0 + p] = T[d * 129 + p];
  }
}

// ---------------- flash attention: hoisted addressing, exp2 softmax, dbuf staging ----------------
// LDS map (bytes): K tiles [2][16384] @0 | V tiles [2][16384] @32768 | P [4][2304] @65536
__global__ __launch_bounds__(256) void attn_kernel(const half_t* __restrict__ qh,
                                                   const half_t* __restrict__ kh,
                                                   const half_t* __restrict__ vt,
                                                   half_t* __restrict__ ah) {
  __shared__ __align__(16) char smem[74752];
  const int tid = threadIdx.x;
  const int lane = tid & 63, w = tid >> 6;
  const int g = lane >> 4, qr = lane & 15;
  const int qt = blockIdx.x, hq = blockIdx.y, b = blockIdx.z;
  const int hkv = hq >> 2;
  const half_t* qbase =
      qh + ((size_t)((b * HQ_N + hq) * S_LEN) + qt * 64 + w * 16 + qr) * HD_N;
  half8 qf[4];
  #pragma unroll
  for (int c = 0; c < 4; ++c) qf[c] = *(const half8*)(qbase + g * 8 + c * 32);
  floatx4 acc[8] = {};
  float m_run = -1e30f, l_run = 0.f;
  const half_t* kg = kh + (size_t)(b * HKV_N + hkv) * L_KV * HD_N;
  const half_t* vg = vt + (size_t)(b * HKV_N + hkv) * HD_N * L_KV;

  // ---- hoisted per-lane LDS base pointers (row&7 == qr&7 for all reads) ----
  const int sw = (qr & 7) << 4;
  const char* kqkP[4];
  #pragma unroll
  for (int c = 0; c < 4; ++c) kqkP[c] = smem + qr * 256 + ((g * 16 + c * 64) ^ sw);
  const char* vP[2];
  #pragma unroll
  for (int kc = 0; kc < 2; ++kc)
    vP[kc] = smem + 32768 + qr * 128 + ((kc * 64 + g * 16) ^ sw);
  char* pwP = smem + 65536 + w * 2304 + qr * 144 + g * 8;
  const char* prP = smem + 65536 + w * 2304 + qr * 144 + g * 16;

  // ---- hoisted global staging pointers ----
  const int r0 = tid >> 4;
  const int c8k = (tid & 15) ^ (r0 & 7);
  const half_t* kp[4];
  #pragma unroll
  for (int j = 0; j < 4; ++j) kp[j] = kg + (size_t)(r0 + 16 * j) * HD_N + c8k * 8;
  const int d0 = tid >> 3;
  const int p8v = (tid & 7) ^ (d0 & 7);
  const half_t* vp[4];
  #pragma unroll
  for (int j = 0; j < 4; ++j) vp[j] = vg + (size_t)(d0 + 32 * j) * L_KV + p8v * 8;
  const int ldsb = (tid & 192) * 16;

#define ISSUE_STAGE(NKB)                                                     \
  do {                                                                       \
    _Pragma("unroll") for (int j2 = 0; j2 < 4; ++j2)                         \
      gload_lds16(kp[j2], smem + (NKB) + ldsb + j2 * 4096);                  \
    _Pragma("unroll") for (int j2 = 0; j2 < 4; ++j2)                         \
      gload_lds16(vp[j2], smem + 32768 + (NKB) + ldsb + j2 * 4096);          \
    _Pragma("unroll") for (int j2 = 0; j2 < 4; ++j2) {                       \
      kp[j2] += 8192; vp[j2] += 64;                                          \
    }                                                                        \
  } while (0)

#define COMPUTE(KB)                                                            \
  do {                                                                         \
    float sc[16];                                                              \
    __builtin_amdgcn_s_setprio(1);                                             \
    _Pragma("unroll") for (int ts = 0; ts < 4; ++ts) {                         \
      floatx4 tq = {0.f, 0.f, 0.f, 0.f};                                       \
      _Pragma("unroll") for (int c = 0; c < 4; ++c)                            \
        tq = __builtin_amdgcn_mfma_f32_16x16x32_f16(                           \
            *(const half8*)(kqkP[c] + (KB) + ts * 4096), qf[c], tq, 0, 0, 0);  \
      sc[ts*4+0]=tq[0]; sc[ts*4+1]=tq[1]; sc[ts*4+2]=tq[2]; sc[ts*4+3]=tq[3];  \
    }                                                                          \
    __builtin_amdgcn_s_setprio(0);                                             \
    float pmax = fmaxf(                                                        \
        max3f(max3f(sc[0], sc[1], sc[2]), max3f(sc[3], sc[4], sc[5]),          \
              max3f(sc[6], sc[7], sc[8])),                                     \
        max3f(max3f(sc[9], sc[10], sc[11]), max3f(sc[12], sc[13], sc[14]),     \
              sc[15]));                                                        \
    pmax = fmaxf(pmax, __shfl_xor(pmax, 16, 64));                              \
    pmax = fmaxf(pmax, __shfl_xor(pmax, 32, 64));                              \
    const bool skip = __all(pmax - m_run <= 8.f);                              \
    const float mnew = skip ? m_run : fmaxf(m_run, pmax);                      \
    float rs = 0.f;                                                            \
    _Pragma("unroll") for (int j = 0; j < 16; ++j) {                           \
      float p;                                                                 \
      asm("v_exp_f32 %0, %1" : "=v"(p) : "v"(sc[j] - mnew));                   \
      sc[j] = p; rs += p;                                                      \
    }                                                                          \
    rs += __shfl_xor(rs, 16, 64);                                              \
    rs += __shfl_xor(rs, 32, 64);                                              \
    if (skip) {                                                                \
      l_run += rs;                                                             \
    } else {                                                                   \
      float scl;                                                               \
      asm("v_exp_f32 %0, %1" : "=v"(scl) : "v"(m_run - mnew));                 \
      l_run = l_run * scl + rs;                                                \
      float f0 = __shfl(scl, g * 4 + 0, 64), f1 = __shfl(scl, g * 4 + 1, 64);  \
      float f2 = __shfl(scl, g * 4 + 2, 64), f3 = __shfl(scl, g * 4 + 3, 64);  \
      _Pragma("unroll") for (int n = 0; n < 8; ++n) {                          \
        acc[n][0] *= f0; acc[n][1] *= f1; acc[n][2] *= f2; acc[n][3] *= f3;    \
      }                                                                        \
      m_run = mnew;                                                            \
    }                                                                          \
    _Pragma("unroll") for (int ts = 0; ts < 4; ++ts) {                         \
      half2v lo = __builtin_bit_cast(                                          \
          half2v, __builtin_amdgcn_cvt_pkrtz(sc[ts * 4 + 0], sc[ts * 4 + 1])); \
      half2v hi = __builtin_bit_cast(                                          \
          half2v, __builtin_amdgcn_cvt_pkrtz(sc[ts * 4 + 2], sc[ts * 4 + 3])); \
      *(half4v*)(pwP + ts * 32) = __builtin_shufflevector(lo, hi, 0, 1, 2, 3); \
    }                                                                          \
    __builtin_amdgcn_s_setprio(1);                                             \
    _Pragma("unroll") for (int kc = 0; kc < 2; ++kc) {                         \
      half8 pf = *(const half8*)(prP + kc * 64);                               \
      _Pragma("unroll") for (int n = 0; n < 8; ++n)                            \
        acc[n] = __builtin_amdgcn_mfma_f32_16x16x32_f16(                       \
            pf, *(const half8*)(vP[kc] + (KB) + n * 2048), acc[n], 0, 0, 0);   \
    }                                                                          \
    __builtin_amdgcn_s_setprio(0);                                             \
  } while (0)

#define ENDBAR                                          \
  do {                                                  \
    asm volatile("s_waitcnt vmcnt(0)" ::: "memory");    \
    __builtin_amdgcn_s_barrier();                       \
  } while (0)

  // prologue: tile 0 -> buf0
  ISSUE_STAGE(0);
  ENDBAR;
  // main: kt 0..29 (buffer parity compile-time via unroll-2)
  for (int it = 0; it < 15; ++it) {
    ISSUE_STAGE(16384); COMPUTE(0);     ENDBAR;
    ISSUE_STAGE(0);     COMPUTE(16384); ENDBAR;
  }
  // kt=30: stage 31 -> buf1, compute buf0
  ISSUE_STAGE(16384); COMPUTE(0); ENDBAR;
  // kt=31
  COMPUTE(16384);

  float il0 = 1.f / __shfl(l_run, g * 4 + 0, 64);
  float il1 = 1.f / __shfl(l_run, g * 4 + 1, 64);
  float il2 = 1.f / __shfl(l_run, g * 4 + 2, 64);
  float il3 = 1.f / __shfl(l_run, g * 4 + 3, 64);
  const int tokb = b * S_LEN + qt * 64 + w * 16 + g * 4;
  #pragma unroll
  for (int n = 0; n < 8; ++n) {
    const int col = hq * HD_N + n * 16 + qr;
    ah[(size_t)(tokb + 0) * DIM + col] = (half_t)(acc[n][0] * il0);
    ah[(size_t)(tokb + 1) * DIM + col] = (half_t)(acc[n][1] * il1);
    ah[(size_t)(tokb + 2) * DIM + col] = (half_t)(acc[n][2] * il2);
    ah[(size_t)(tokb + 3) * DIM + col] = (half_t)(acc[n][3] * il3);
  }
#undef ISSUE_STAGE
#undef COMPUTE
#undef ENDBAR
}

extern "C" void kernel_launch(void* const* d_in, const int* in_sizes, int n_in,
                              void* d_out, int out_size, void* d_ws, size_t ws_size,
                              hipStream_t stream) {
  (void)in_sizes; (void)n_in; (void)out_size; (void)ws_size;
  const float* x = (const float*)d_in[0];
  const float* wq = (const float*)d_in[1];
  const float* wk = (const float*)d_in[2];
  const float* wv = (const float*)d_in[3];
  const float* wo = (const float*)d_in[4];
  const float* fc = (const float*)d_in[5];
  const float* fs = (const float*)d_in[6];
  const float* ck = (const float*)d_in[7];
  const float* cv = (const float*)d_in[8];

  char* ws = (char*)d_ws;
  size_t off = 0;
  auto alloc = [&](size_t bytes) {
    char* p = ws + off;
    off += (bytes + 255) & ~(size_t)255;
    return p;
  };
  half_t* xh     = (half_t*)alloc((size_t)TOK * DIM * 2);     // later qh
  half_t* W      = (half_t*)alloc((size_t)NQKV * DIM * 2);    // wq^T|wk^T|wv^T; later ah
  half_t* qkvf16 = (half_t*)alloc((size_t)TOK * NQKV * 2);    // later woT
  half_t* kh     = (half_t*)alloc((size_t)B_SZ * HKV_N * L_KV * HD_N * 2);
  half_t* vth    = (half_t*)alloc((size_t)B_SZ * HKV_N * HD_N * L_KV * 2);
  half_t* qh     = xh;       // alias: xh dead after qkv GEMM
  half_t* ah     = W;        // alias: W dead after qkv GEMM
  half_t* woT    = qkvf16;   // alias: qkvf16 dead after packs

  // 1. convert x to f16
  conv_x_kernel<<<dim3(TOK * DIM / 4 / 256), dim3(256), 0, stream>>>(x, xh);
  // 2. weight transposes into concatenated [6144][4096]
  conv_transpose<<<dim3(DIM / 64, DIM / 64), dim3(256), 0, stream>>>(wq, W, DIM, DIM);
  conv_transpose<<<dim3(NKV / 64, DIM / 64), dim3(256), 0, stream>>>(wk, W + (size_t)DIM * DIM, DIM, NKV);
  conv_transpose<<<dim3(NKV / 64, DIM / 64), dim3(256), 0, stream>>>(wv, W + (size_t)(DIM + NKV) * DIM, DIM, NKV);
  // 3. fused qkv projection: [4096][6144]
  gemm256<half_t><<<dim3((TOK / 256) * (NQKV / 256)), dim3(512), 0, stream>>>(xh, W, qkvf16, TOK, NQKV, DIM);
  // 4. rope + pack
  pack_q_kernel<<<dim3(B_SZ * S_LEN * HQ_N * 64 / 256), dim3(256), 0, stream>>>(qkvf16, fc, fs, qh);
  pack_k_kernel<<<dim3(B_SZ * L_KV * HKV_N * 64 / 256), dim3(256), 0, stream>>>(qkvf16, ck, fc, fs, kh);
  pack_vt_kernel<<<dim3(B_SZ * HKV_N * (L_KV / 128)), dim3(256), 0, stream>>>(qkvf16, cv, vth);
  // 5. attention (writes ah = old W region)
  attn_kernel<<<dim3(S_LEN / 64, HQ_N, B_SZ), dim3(256), 0, stream>>>(qh, kh, vth, ah);
  // 6. wo transpose (into qkvf16 region), then output projection
  conv_transpose<<<dim3(DIM / 64, DIM / 64), dim3(256), 0, stream>>>(wo, woT, DIM, DIM);
  gemm256<float><<<dim3((TOK / 256) * (DIM / 256)), dim3(512), 0, stream>>>(ah, woT, (float*)d_out, TOK, DIM, DIM);
}

// Round 5
// 665.766 us; speedup vs baseline: 1.4670x; 1.0540x over previous
//
#include <hip/hip_runtime.h>

typedef _Float16 half_t;
typedef _Float16 half8 __attribute__((ext_vector_type(8)));
typedef _Float16 half4v __attribute__((ext_vector_type(4)));
typedef _Float16 half2v __attribute__((ext_vector_type(2)));
typedef float floatx4 __attribute__((ext_vector_type(4)));

#define TOK 4096
#define DIM 4096
#define S_LEN 1024
#define B_SZ 4
#define HQ_N 32
#define HKV_N 8
#define HD_N 128
#define L_KV 2048
#define NKV 1024
#define NQKV 6144
#define QK_SCALE 0.08838834764831845f
#define LOG2E 1.4426950408889634f

__device__ __forceinline__ void gload_lds16(const void* g, void* l) {
  __builtin_amdgcn_global_load_lds(
      (const __attribute__((address_space(1))) unsigned int*)g,
      (__attribute__((address_space(3))) unsigned int*)l, 16, 0, 0);
}

__device__ __forceinline__ float max3f(float a, float b, float c) {
  return fmaxf(fmaxf(a, b), c);   // fuses to v_max3_f32
}

// ---------------- elementwise f32 -> f16 ----------------
__global__ __launch_bounds__(256) void conv_x_kernel(const float* __restrict__ x,
                                                     half_t* __restrict__ xh) {
  int t = blockIdx.x * 256 + threadIdx.x;
  floatx4 v = *((const floatx4*)x + t);
  half4v o;
  o[0] = (half_t)v[0]; o[1] = (half_t)v[1]; o[2] = (half_t)v[2]; o[3] = (half_t)v[3];
  *((half4v*)xh + t) = o;
}

// ---------------- transpose + convert: out[n][k] = f16(in[k][n]) ----------------
__global__ __launch_bounds__(256) void conv_transpose(const float* __restrict__ in,
                                                      half_t* __restrict__ out,
                                                      int K, int N) {
  __shared__ half_t T[64 * 65];
  const int tid = threadIdx.x;
  const int n0 = blockIdx.x * 64, k0 = blockIdx.y * 64;
  #pragma unroll
  for (int i = 0; i < 16; ++i) {
    int idx = i * 256 + tid;
    int r = idx >> 6, c = idx & 63;
    T[c * 65 + r] = (half_t)in[(size_t)(k0 + r) * N + n0 + c];
  }
  __syncthreads();
  #pragma unroll
  for (int i = 0; i < 16; ++i) {
    int idx = i * 256 + tid;
    int rn = idx >> 6, ck = idx & 63;
    out[(size_t)(n0 + rn) * K + k0 + ck] = T[rn * 65 + ck];
  }
}

// ---------------- 256^2 8-phase GEMM (T1..T5): C[M][N] = A[M][K] * BT[N][K]^T ----------------
template <typename OT>
__global__ __launch_bounds__(512) void gemm256(const half_t* __restrict__ A,
                                               const half_t* __restrict__ BT,
                                               OT* __restrict__ C,
                                               int M, int N, int K) {
  __shared__ __align__(16) char smem[131072];   // A dbuf 64K | B dbuf 64K
  const int tid = threadIdx.x;
  const int lane = tid & 63, w = tid >> 6;
  const int g = lane >> 4, qr = lane & 15;
  const int wm = w >> 2, wn = w & 3;
  const int nbx = N >> 8;
  const int nwg = gridDim.x;
  const int cpx = nwg >> 3;
  const int bid = ((int)blockIdx.x & 7) * cpx + ((int)blockIdx.x >> 3);
  const int bx = bid % nbx, by = bid / nbx;
  const int m0 = by << 8, n0 = bx << 8;
  const int NT = K >> 6;

  const int ch0 = tid, ch1 = tid + 512;
  const int sr0 = ch0 >> 3, sc0 = (ch0 & 7) ^ (sr0 & 7);
  const int sr1 = ch1 >> 3, sc1 = (ch1 & 7) ^ (sr1 & 7);
  const size_t so0 = (size_t)sr0 * K + sc0 * 8;
  const size_t so1 = (size_t)sr1 * K + sc1 * 8;
  const int wb = (w * 64) * 16;
  const half_t* Ab = A + (size_t)m0 * K;
  const half_t* Bb = BT + (size_t)n0 * K;

#define G_STAGE(gsrc, ldst)                                   \
  do {                                                        \
    gload_lds16((gsrc) + so0, (char*)(ldst) + wb);            \
    gload_lds16((gsrc) + so1, (char*)(ldst) + wb + 8192);     \
  } while (0)

#define FRAG(base, row, kb) \
  (*(const half8*)((base) + ((((row) * 128) + (kb)) ^ (((row) & 7) << 4))))

  G_STAGE(Ab, smem);
  G_STAGE(Ab + (size_t)128 * K, smem + 16384);
  G_STAGE(Bb, smem + 65536);
  G_STAGE(Bb + (size_t)128 * K, smem + 81920);
  G_STAGE(Ab + 64, smem + 32768);
  G_STAGE(Bb + 64, smem + 98304);
  asm volatile("s_waitcnt vmcnt(4)" ::: "memory");
  __builtin_amdgcn_s_barrier();

  floatx4 acc[8][4] = {};
  half8 aF[4][2], bF0[2][2], bF1[2][2];

#define MFMA_Q(mh, nh, BF)                                                     \
  do {                                                                         \
    __builtin_amdgcn_s_setprio(1);                                             \
    _Pragma("unroll") for (int mf = 0; mf < 4; ++mf)                           \
    _Pragma("unroll") for (int nf = 0; nf < 2; ++nf)                           \
    _Pragma("unroll") for (int kk = 0; kk < 2; ++kk)                           \
      acc[(mh)*4 + mf][(nh)*2 + nf] = __builtin_amdgcn_mfma_f32_16x16x32_f16(  \
          aF[mf][kk], BF[nf][kk], acc[(mh)*4 + mf][(nh)*2 + nf], 0, 0, 0);     \
    __builtin_amdgcn_s_setprio(0);                                             \
  } while (0)

  for (int t = 0; t < NT; ++t) {
    const char* Ac = smem + ((t & 1) ? 32768 : 0);
    const char* Bc = smem + 65536 + ((t & 1) ? 32768 : 0);
    char* An = smem + ((t & 1) ? 0 : 32768);
    char* Bn = smem + 65536 + ((t & 1) ? 0 : 32768);
    const int t1 = (t + 1 < NT) ? t + 1 : NT - 1;
    const int t2 = (t + 2 < NT) ? t + 2 : NT - 1;
    // phase 0
    #pragma unroll
    for (int mf = 0; mf < 4; ++mf)
      #pragma unroll
      for (int kk = 0; kk < 2; ++kk)
        aF[mf][kk] = FRAG(Ac, wm * 128 + mf * 16 + qr, kk * 64 + g * 16);
    #pragma unroll
    for (int nf = 0; nf < 2; ++nf)
      #pragma unroll
      for (int kk = 0; kk < 2; ++kk)
        bF0[nf][kk] = FRAG(Bc, wn * 64 + nf * 16 + qr, kk * 64 + g * 16);
    G_STAGE(Ab + (size_t)128 * K + t1 * 64, An + 16384);
    __builtin_amdgcn_s_barrier();
    asm volatile("s_waitcnt lgkmcnt(0)" ::: "memory");
    MFMA_Q(0, 0, bF0);
    __builtin_amdgcn_s_barrier();
    // phase 1
    #pragma unroll
    for (int nf = 0; nf < 2; ++nf)
      #pragma unroll
      for (int kk = 0; kk < 2; ++kk)
        bF1[nf][kk] = FRAG(Bc, wn * 64 + 32 + nf * 16 + qr, kk * 64 + g * 16);
    G_STAGE(Bb + (size_t)128 * K + t1 * 64, Bn + 16384);
    __builtin_amdgcn_s_barrier();
    asm volatile("s_waitcnt lgkmcnt(0)" ::: "memory");
    MFMA_Q(0, 1, bF1);
    __builtin_amdgcn_s_barrier();
    // phase 2
    #pragma unroll
    for (int mf = 0; mf < 4; ++mf)
      #pragma unroll
      for (int kk = 0; kk < 2; ++kk)
        aF[mf][kk] = FRAG(Ac, wm * 128 + 64 + mf * 16 + qr, kk * 64 + g * 16);
    __builtin_amdgcn_s_barrier();
    asm volatile("s_waitcnt lgkmcnt(0)" ::: "memory");
    MFMA_Q(1, 1, bF1);
    __builtin_amdgcn_s_barrier();
    // phase 3
    G_STAGE(Ab + (size_t)t2 * 64, (char*)Ac);
    G_STAGE(Bb + (size_t)t2 * 64, (char*)Bc);
    __builtin_amdgcn_s_barrier();
    MFMA_Q(1, 0, bF0);
    asm volatile("s_waitcnt vmcnt(4)" ::: "memory");
    __builtin_amdgcn_s_barrier();
  }
  #pragma unroll
  for (int mh = 0; mh < 2; ++mh)
    #pragma unroll
    for (int mf = 0; mf < 4; ++mf) {
      const int rb = m0 + wm * 128 + mh * 64 + mf * 16 + g * 4;
      #pragma unroll
      for (int nh = 0; nh < 2; ++nh)
        #pragma unroll
        for (int nf = 0; nf < 2; ++nf) {
          const int col = n0 + wn * 64 + nh * 32 + nf * 16 + qr;
          floatx4 v = acc[mh * 4 + mf][nh * 2 + nf];
          #pragma unroll
          for (int r = 0; r < 4; ++r)
            C[(size_t)(rb + r) * N + col] = (OT)v[r];
        }
    }
#undef G_STAGE
#undef FRAG
#undef MFMA_Q
}

// ---------------- pack q: rope + scale*log2e -> [B][HQ][S][HD] f16 ----------------
__global__ __launch_bounds__(256) void pack_q_kernel(const half_t* __restrict__ qkv,
                                                     const float* __restrict__ cosT,
                                                     const float* __restrict__ sinT,
                                                     half_t* __restrict__ qh) {
  int t = blockIdx.x * 256 + threadIdx.x;
  int j = t & 63;
  int hq = (t >> 6) & 31;
  int tok = t >> 11;
  int s = tok & 1023;
  int b = tok >> 10;
  const half_t* src = qkv + (size_t)tok * NQKV + hq * HD_N + 2 * j;
  float xr = (float)src[0], xi = (float)src[1];
  float c = cosT[s * 64 + j], sn = sinT[s * 64 + j];
  const float QS2 = QK_SCALE * LOG2E;   // exp2-domain scores
  half2v o;
  o[0] = (half_t)((xr * c - xi * sn) * QS2);
  o[1] = (half_t)((xr * sn + xi * c) * QS2);
  *(half2v*)(qh + ((size_t)((b * HQ_N + hq) * S_LEN + s)) * HD_N + 2 * j) = o;
}

// ---------------- pack keys: cache + rope(new) -> [B][HKV][L][HD] f16 ----------------
__global__ __launch_bounds__(256) void pack_k_kernel(const half_t* __restrict__ qkv,
                                                     const float* __restrict__ cache_k,
                                                     const float* __restrict__ cosT,
                                                     const float* __restrict__ sinT,
                                                     half_t* __restrict__ kh) {
  int t = blockIdx.x * 256 + threadIdx.x;
  int j = t & 63;
  int h = (t >> 6) & 7;
  int pos = (t >> 9) & 2047;
  int b = t >> 20;
  float xr, xi;
  if (pos < 1024) {
    const float* src = cache_k + ((size_t)(b * L_KV + pos) * HKV_N + h) * HD_N + 2 * j;
    xr = src[0]; xi = src[1];
  } else {
    int s = pos - 1024;
    const half_t* src = qkv + (size_t)(b * S_LEN + s) * NQKV + DIM + h * HD_N + 2 * j;
    float r0 = (float)src[0], i0 = (float)src[1];
    float c = cosT[s * 64 + j], sn = sinT[s * 64 + j];
    xr = r0 * c - i0 * sn;
    xi = r0 * sn + i0 * c;
  }
  half2v o; o[0] = (half_t)xr; o[1] = (half_t)xi;
  *(half2v*)(kh + ((size_t)(b * HKV_N + h) * L_KV + pos) * HD_N + 2 * j) = o;
}

// ---------------- pack values transposed: -> [B][HKV][HD][L] f16 ----------------
__global__ __launch_bounds__(256) void pack_vt_kernel(const half_t* __restrict__ qkv,
                                                      const float* __restrict__ cache_v,
                                                      half_t* __restrict__ vt) {
  __shared__ half_t T[128 * 129];
  const int tid = threadIdx.x;
  const int blk = blockIdx.x;
  const int pt = blk & 15;
  const int h = (blk >> 4) & 7;
  const int b = blk >> 7;
  const int p0 = pt * 128;
  #pragma unroll
  for (int i = 0; i < 64; ++i) {
    int idx = i * 256 + tid;
    int p = idx >> 7, d = idx & 127;
    int pos = p0 + p;
    float v;
    if (pos < 1024)
      v = cache_v[((size_t)(b * L_KV + pos) * HKV_N + h) * HD_N + d];
    else
      v = (float)qkv[(size_t)(b * S_LEN + (pos - 1024)) * NQKV + DIM + NKV + h * HD_N + d];
    T[d * 129 + p] = (half_t)v;
  }
  __syncthreads();
  #pragma unroll
  for (int i = 0; i < 64; ++i) {
    int idx = i * 256 + tid;
    int d = idx >> 7, p = idx & 127;
    vt[((size_t)(b * HKV_N + h) * HD_N + d) * L_KV + p0 + p] = T[d * 129 + p];
  }
}

// ---------------- flash attention: QBLK=128 (2 q-sets/wave), exp2 softmax, dbuf staging ----------------
// LDS map (bytes): K tiles [2][16384] @0 | V tiles [2][16384] @32768 | P [4][2304] @65536
__global__ __launch_bounds__(256, 2) void attn_kernel(const half_t* __restrict__ qh,
                                                      const half_t* __restrict__ kh,
                                                      const half_t* __restrict__ vt,
                                                      half_t* __restrict__ ah) {
  __shared__ __align__(16) char smem[74752];
  const int tid = threadIdx.x;
  const int lane = tid & 63, w = tid >> 6;
  const int g = lane >> 4, qr = lane & 15;
  const int qt = blockIdx.x, hq = blockIdx.y, b = blockIdx.z;
  const int hkv = hq >> 2;
  const half_t* qbase =
      qh + ((size_t)((b * HQ_N + hq) * S_LEN) + qt * 128 + w * 16 + qr) * HD_N;
  half8 qfA[4], qfB[4];
  #pragma unroll
  for (int c = 0; c < 4; ++c) {
    qfA[c] = *(const half8*)(qbase + g * 8 + c * 32);
    qfB[c] = *(const half8*)(qbase + (size_t)64 * HD_N + g * 8 + c * 32);
  }
  floatx4 accA[8] = {}, accB[8] = {};
  float mA = -1e30f, lA = 0.f, mB = -1e30f, lB = 0.f;
  const half_t* kg = kh + (size_t)(b * HKV_N + hkv) * L_KV * HD_N;
  const half_t* vg = vt + (size_t)(b * HKV_N + hkv) * HD_N * L_KV;

  // ---- hoisted per-lane LDS base pointers (row&7 == qr&7 for all reads) ----
  const int sw = (qr & 7) << 4;
  const char* kqkP[4];
  #pragma unroll
  for (int c = 0; c < 4; ++c) kqkP[c] = smem + qr * 256 + ((g * 16 + c * 64) ^ sw);
  const char* vP[2];
  #pragma unroll
  for (int kc = 0; kc < 2; ++kc)
    vP[kc] = smem + 32768 + qr * 128 + ((kc * 64 + g * 16) ^ sw);
  char* pwP = smem + 65536 + w * 2304 + qr * 144 + g * 8;
  const char* prP = smem + 65536 + w * 2304 + qr * 144 + g * 16;

  // ---- hoisted global staging pointers ----
  const int r0 = tid >> 4;
  const int c8k = (tid & 15) ^ (r0 & 7);
  const half_t* kp[4];
  #pragma unroll
  for (int j = 0; j < 4; ++j) kp[j] = kg + (size_t)(r0 + 16 * j) * HD_N + c8k * 8;
  const int d0 = tid >> 3;
  const int p8v = (tid & 7) ^ (d0 & 7);
  const half_t* vp[4];
  #pragma unroll
  for (int j = 0; j < 4; ++j) vp[j] = vg + (size_t)(d0 + 32 * j) * L_KV + p8v * 8;
  const int ldsb = (tid & 192) * 16;

#define ISSUE_STAGE(NKB)                                                     \
  do {                                                                       \
    _Pragma("unroll") for (int j2 = 0; j2 < 4; ++j2)                         \
      gload_lds16(kp[j2], smem + (NKB) + ldsb + j2 * 4096);                  \
    _Pragma("unroll") for (int j2 = 0; j2 < 4; ++j2)                         \
      gload_lds16(vp[j2], smem + 32768 + (NKB) + ldsb + j2 * 4096);          \
    _Pragma("unroll") for (int j2 = 0; j2 < 4; ++j2) {                       \
      kp[j2] += 8192; vp[j2] += 64;                                          \
    }                                                                        \
  } while (0)

#define QKT(QF, SC, KB)                                                        \
  do {                                                                         \
    __builtin_amdgcn_s_setprio(1);                                             \
    _Pragma("unroll") for (int ts = 0; ts < 4; ++ts) {                         \
      floatx4 tq = {0.f, 0.f, 0.f, 0.f};                                       \
      _Pragma("unroll") for (int c = 0; c < 4; ++c)                            \
        tq = __builtin_amdgcn_mfma_f32_16x16x32_f16(                           \
            *(const half8*)(kqkP[c] + (KB) + ts * 4096), QF[c], tq, 0, 0, 0);  \
      SC[ts*4+0]=tq[0]; SC[ts*4+1]=tq[1]; SC[ts*4+2]=tq[2]; SC[ts*4+3]=tq[3];  \
    }                                                                          \
    __builtin_amdgcn_s_setprio(0);                                             \
  } while (0)

#define SOFTPV(SC, ACC, MR, LR, KB)                                            \
  do {                                                                         \
    float pmax = fmaxf(                                                        \
        max3f(max3f(SC[0], SC[1], SC[2]), max3f(SC[3], SC[4], SC[5]),          \
              max3f(SC[6], SC[7], SC[8])),                                     \
        max3f(max3f(SC[9], SC[10], SC[11]), max3f(SC[12], SC[13], SC[14]),     \
              SC[15]));                                                        \
    pmax = fmaxf(pmax, __shfl_xor(pmax, 16, 64));                              \
    pmax = fmaxf(pmax, __shfl_xor(pmax, 32, 64));                              \
    const bool skip = __all(pmax - MR <= 8.f);                                 \
    const float mnew = skip ? MR : fmaxf(MR, pmax);                            \
    float rs = 0.f;                                                            \
    _Pragma("unroll") for (int j = 0; j < 16; ++j) {                           \
      float p;                                                                 \
      asm("v_exp_f32 %0, %1" : "=v"(p) : "v"(SC[j] - mnew));                   \
      SC[j] = p; rs += p;                                                      \
    }                                                                          \
    rs += __shfl_xor(rs, 16, 64);                                              \
    rs += __shfl_xor(rs, 32, 64);                                              \
    if (skip) {                                                                \
      LR += rs;                                                                \
    } else {                                                                   \
      float scl;                                                               \
      asm("v_exp_f32 %0, %1" : "=v"(scl) : "v"(MR - mnew));                    \
      LR = LR * scl + rs;                                                      \
      float f0 = __shfl(scl, g * 4 + 0, 64), f1 = __shfl(scl, g * 4 + 1, 64);  \
      float f2 = __shfl(scl, g * 4 + 2, 64), f3 = __shfl(scl, g * 4 + 3, 64);  \
      _Pragma("unroll") for (int n = 0; n < 8; ++n) {                          \
        ACC[n][0] *= f0; ACC[n][1] *= f1; ACC[n][2] *= f2; ACC[n][3] *= f3;    \
      }                                                                        \
      MR = mnew;                                                               \
    }                                                                          \
    _Pragma("unroll") for (int ts = 0; ts < 4; ++ts) {                         \
      half2v lo = __builtin_bit_cast(                                          \
          half2v, __builtin_amdgcn_cvt_pkrtz(SC[ts * 4 + 0], SC[ts * 4 + 1])); \
      half2v hi = __builtin_bit_cast(                                          \
          half2v, __builtin_amdgcn_cvt_pkrtz(SC[ts * 4 + 2], SC[ts * 4 + 3])); \
      *(half4v*)(pwP + ts * 32) = __builtin_shufflevector(lo, hi, 0, 1, 2, 3); \
    }                                                                          \
    __builtin_amdgcn_s_setprio(1);                                             \
    _Pragma("unroll") for (int kc = 0; kc < 2; ++kc) {                         \
      half8 pf = *(const half8*)(prP + kc * 64);                               \
      _Pragma("unroll") for (int n = 0; n < 8; ++n)                            \
        ACC[n] = __builtin_amdgcn_mfma_f32_16x16x32_f16(                       \
            pf, *(const half8*)(vP[kc] + (KB) + n * 2048), ACC[n], 0, 0, 0);   \
    }                                                                          \
    __builtin_amdgcn_s_setprio(0);                                             \
  } while (0)

#define COMPUTE2(KB)                       \
  do {                                     \
    float scA[16], scB[16];                \
    QKT(qfA, scA, KB);                     \
    QKT(qfB, scB, KB);                     \
    SOFTPV(scA, accA, mA, lA, KB);         \
    SOFTPV(scB, accB, mB, lB, KB);         \
  } while (0)

#define ENDBAR                                          \
  do {                                                  \
    asm volatile("s_waitcnt vmcnt(0)" ::: "memory");    \
    __builtin_amdgcn_s_barrier();                       \
  } while (0)

  // prologue: tile 0 -> buf0
  ISSUE_STAGE(0);
  ENDBAR;
  // main: kt 0..29 (buffer parity compile-time via unroll-2)
  for (int it = 0; it < 15; ++it) {
    ISSUE_STAGE(16384); COMPUTE2(0);     ENDBAR;
    ISSUE_STAGE(0);     COMPUTE2(16384); ENDBAR;
  }
  // kt=30: stage 31 -> buf1, compute buf0
  ISSUE_STAGE(16384); COMPUTE2(0); ENDBAR;
  // kt=31
  COMPUTE2(16384);

#define WRITE_OUT(ACC, LR, SOFF)                                            \
  do {                                                                      \
    float il0 = 1.f / __shfl(LR, g * 4 + 0, 64);                            \
    float il1 = 1.f / __shfl(LR, g * 4 + 1, 64);                            \
    float il2 = 1.f / __shfl(LR, g * 4 + 2, 64);                            \
    float il3 = 1.f / __shfl(LR, g * 4 + 3, 64);                            \
    const int tokb = b * S_LEN + qt * 128 + (SOFF) + w * 16 + g * 4;        \
    _Pragma("unroll") for (int n = 0; n < 8; ++n) {                         \
      const int col = hq * HD_N + n * 16 + qr;                              \
      ah[(size_t)(tokb + 0) * DIM + col] = (half_t)(ACC[n][0] * il0);       \
      ah[(size_t)(tokb + 1) * DIM + col] = (half_t)(ACC[n][1] * il1);       \
      ah[(size_t)(tokb + 2) * DIM + col] = (half_t)(ACC[n][2] * il2);       \
      ah[(size_t)(tokb + 3) * DIM + col] = (half_t)(ACC[n][3] * il3);       \
    }                                                                       \
  } while (0)

  WRITE_OUT(accA, lA, 0);
  WRITE_OUT(accB, lB, 64);
#undef ISSUE_STAGE
#undef QKT
#undef SOFTPV
#undef COMPUTE2
#undef ENDBAR
#undef WRITE_OUT
}

extern "C" void kernel_launch(void* const* d_in, const int* in_sizes, int n_in,
                              void* d_out, int out_size, void* d_ws, size_t ws_size,
                              hipStream_t stream) {
  (void)in_sizes; (void)n_in; (void)out_size; (void)ws_size;
  const float* x = (const float*)d_in[0];
  const float* wq = (const float*)d_in[1];
  const float* wk = (const float*)d_in[2];
  const float* wv = (const float*)d_in[3];
  const float* wo = (const float*)d_in[4];
  const float* fc = (const float*)d_in[5];
  const float* fs = (const float*)d_in[6];
  const float* ck = (const float*)d_in[7];
  const float* cv = (const float*)d_in[8];

  char* ws = (char*)d_ws;
  size_t off = 0;
  auto alloc = [&](size_t bytes) {
    char* p = ws + off;
    off += (bytes + 255) & ~(size_t)255;
    return p;
  };
  half_t* xh     = (half_t*)alloc((size_t)TOK * DIM * 2);     // later qh
  half_t* W      = (half_t*)alloc((size_t)NQKV * DIM * 2);    // wq^T|wk^T|wv^T; later ah
  half_t* qkvf16 = (half_t*)alloc((size_t)TOK * NQKV * 2);    // later woT
  half_t* kh     = (half_t*)alloc((size_t)B_SZ * HKV_N * L_KV * HD_N * 2);
  half_t* vth    = (half_t*)alloc((size_t)B_SZ * HKV_N * HD_N * L_KV * 2);
  half_t* qh     = xh;       // alias: xh dead after qkv GEMM
  half_t* ah     = W;        // alias: W dead after qkv GEMM
  half_t* woT    = qkvf16;   // alias: qkvf16 dead after packs

  // 1. convert x to f16
  conv_x_kernel<<<dim3(TOK * DIM / 4 / 256), dim3(256), 0, stream>>>(x, xh);
  // 2. weight transposes into concatenated [6144][4096]
  conv_transpose<<<dim3(DIM / 64, DIM / 64), dim3(256), 0, stream>>>(wq, W, DIM, DIM);
  conv_transpose<<<dim3(NKV / 64, DIM / 64), dim3(256), 0, stream>>>(wk, W + (size_t)DIM * DIM, DIM, NKV);
  conv_transpose<<<dim3(NKV / 64, DIM / 64), dim3(256), 0, stream>>>(wv, W + (size_t)(DIM + NKV) * DIM, DIM, NKV);
  // 3. fused qkv projection: [4096][6144]
  gemm256<half_t><<<dim3((TOK / 256) * (NQKV / 256)), dim3(512), 0, stream>>>(xh, W, qkvf16, TOK, NQKV, DIM);
  // 4. rope + pack
  pack_q_kernel<<<dim3(B_SZ * S_LEN * HQ_N * 64 / 256), dim3(256), 0, stream>>>(qkvf16, fc, fs, qh);
  pack_k_kernel<<<dim3(B_SZ * L_KV * HKV_N * 64 / 256), dim3(256), 0, stream>>>(qkvf16, ck, fc, fs, kh);
  pack_vt_kernel<<<dim3(B_SZ * HKV_N * (L_KV / 128)), dim3(256), 0, stream>>>(qkvf16, cv, vth);
  // 5. attention (writes ah = old W region)
  attn_kernel<<<dim3(S_LEN / 128, HQ_N, B_SZ), dim3(256), 0, stream>>>(qh, kh, vth, ah);
  // 6. wo transpose (into qkvf16 region), then output projection
  conv_transpose<<<dim3(DIM / 64, DIM / 64), dim3(256), 0, stream>>>(wo, woT, DIM, DIM);
  gemm256<float><<<dim3((TOK / 256) * (DIM / 256)), dim3(512), 0, stream>>>(ah, woT, (float*)d_out, TOK, DIM, DIM);
}